// Round 9
// baseline (345.568 us; speedup 1.0000x reference)
//
#include <hip/hip_runtime.h>
#include <math.h>

#define B_   64
#define L_   196
#define C_   768
#define K_   8192
#define R_   8
#define HW_  14
#define M_   (B_*L_)     // 12544
#define NH_  8
#define DH_  96
#define BP_  16
#define NT_  32

typedef unsigned short ushort_t;
typedef __attribute__((ext_vector_type(8))) short short8v;   // 8 bf16 (4 VGPR)
typedef __attribute__((ext_vector_type(4))) float f32x4;     // MFMA 16x16 f32 acc
typedef __attribute__((ext_vector_type(4))) int   i32x4;     // MFMA i8 operands/acc

// ---------------- utilities ----------------
__device__ inline float wave_reduce_sum(float v) {
    #pragma unroll
    for (int o = 32; o >= 1; o >>= 1) v += __shfl_xor(v, o, 64);
    return v;
}
__device__ inline float wave_reduce_max(float v) {
    #pragma unroll
    for (int o = 32; o >= 1; o >>= 1) v = fmaxf(v, __shfl_xor(v, o, 64));
    return v;
}

__device__ inline ushort_t f2bf_rne(float f) {
    unsigned u = __float_as_uint(f);
    unsigned r = u + 0x7fffu + ((u >> 16) & 1u);
    return (ushort_t)(r >> 16);
}
__device__ inline float bf2f(ushort_t h) { return __uint_as_float(((unsigned)h) << 16); }

__device__ inline char q8(float f, float s) {
    int q = __float2int_rn(f * s);
    return (char)(q < -127 ? -127 : (q > 127 ? 127 : q));
}

__device__ inline void gload_lds16(const void* gsrc, void* ldst) {
    __builtin_amdgcn_global_load_lds(
        (const __attribute__((address_space(1))) unsigned int*)gsrc,
        (__attribute__((address_space(3))) unsigned int*)ldst, 16, 0, 0);
}

// merge two sorted pairs -> sorted top-2 of union (lowest-index tie-break)
__device__ inline void top2_merge(float& v1, int& i1, float& v2, int& i2,
                                  float w1, int j1, float w2, int j2) {
    bool fw = (v1 < w1) || (v1 == w1 && i1 <= j1);
    float a1 = fw ? v1 : w1;  int ai1 = fw ? i1 : j1;
    float lb = fw ? w1 : v1;  int lbi = fw ? j1 : i1;
    float wsv = fw ? v2 : w2; int wsi = fw ? i2 : j2;
    bool sb = (lb < wsv) || (lb == wsv && lbi < wsi);
    v1 = a1; i1 = ai1;
    v2 = sb ? lb : wsv; i2 = sb ? lbi : wsi;
}

__device__ inline void ce4(float& v0, int& j0, float& v1, int& j1) {
    bool sw = (v1 < v0) || (v1 == v0 && j1 < j0);
    float tv = sw ? v1 : v0, uv = sw ? v0 : v1;
    int tj = sw ? j1 : j0, uj = sw ? j0 : j1;
    v0 = tv; j0 = tj; v1 = uv; j1 = uj;
}
__device__ inline void pickmin(float& v, int& j, float bv, int bj) {
    if (bv < v || (bv == v && bj < j)) { v = bv; j = bj; }
}

// ---------------- codebook -> int8 frags + norms (fused) ----------------
// CBq layout: [cb_g(512)][kb(12)][l(64)][e(16)] bytes; code=cb_g*16+(l&15), k=kb*64+(l>>4)*16+e
__global__ __launch_bounds__(256) void cbq_kernel(const float* __restrict__ CB,
                                                  char* __restrict__ CBq,
                                                  float* __restrict__ cnq) {
    __shared__ float xs[16 * 776];
    const int t = threadIdx.x;
    const int blk = blockIdx.x;
    const float4* src = (const float4*)(CB + (size_t)blk * 16 * C_);
    #pragma unroll
    for (int i = 0; i < 12; ++i) {
        int idx4 = t + i * 256;
        int r = idx4 / 192, c4 = idx4 - r * 192;
        ((float4*)(xs + r * 776))[c4] = src[idx4];
    }
    __syncthreads();
    #pragma unroll
    for (int i = 0; i < 3; ++i) {
        int s = t + i * 256;
        int kb = s >> 6, l = s & 63;
        int row = l & 15;
        int k0 = kb * 64 + ((l >> 4) << 4);
        union { char c[16]; i32x4 v; } Q;
        #pragma unroll
        for (int e = 0; e < 16; ++e) Q.c[e] = q8(xs[row * 776 + k0 + e], 32.f);
        *(i32x4*)&CBq[(((size_t)blk * 12 + kb) << 10) + l * 16] = Q.v;
    }
    // norms: thread t -> row t&15, chunk t>>4 (48 elems)
    int row = t & 15, chunk = t >> 4;
    float sum = 0.f;
    #pragma unroll
    for (int j = 0; j < 48; ++j) { float v = xs[row * 776 + chunk * 48 + j]; sum += v * v; }
    sum += __shfl_xor(sum, 16, 64);
    sum += __shfl_xor(sum, 32, 64);
    __shared__ float red[4][16];
    if ((t & 63) < 16) red[t >> 6][t & 15] = sum;
    __syncthreads();
    if (t < 16) cnq[blk * 16 + t] = (red[0][t] + red[1][t] + red[2][t] + red[3][t]) * 1024.f;
}

// ---------------- A -> int8 frags ----------------
__global__ __launch_bounds__(256) void aq_kernel(const float* __restrict__ X,
                                                 char* __restrict__ Aq) {
    __shared__ float xs[16 * 776];
    const int t = threadIdx.x;
    const int rg = blockIdx.x;
    const float4* src = (const float4*)(X + (size_t)rg * 16 * C_);
    #pragma unroll
    for (int i = 0; i < 12; ++i) {
        int idx4 = t + i * 256;
        int r = idx4 / 192, c4 = idx4 - r * 192;
        ((float4*)(xs + r * 776))[c4] = src[idx4];
    }
    __syncthreads();
    #pragma unroll
    for (int i = 0; i < 3; ++i) {
        int s = t + i * 256;
        int kb = s >> 6, l = s & 63;
        int row = l & 15;
        int k0 = kb * 64 + ((l >> 4) << 4);
        union { char c[16]; i32x4 v; } Q;
        #pragma unroll
        for (int e = 0; e < 16; ++e) Q.c[e] = q8(xs[row * 776 + k0 + e], 32.f);
        *(i32x4*)&Aq[(((size_t)rg * 12 + kb) << 10) + l * 16] = Q.v;
    }
}

// ---------------- conv weights: att bf16 frags + ex int8 frags ----------------
__global__ __launch_bounds__(256) void wsplit_kernel(const float* __restrict__ att_w,
                                                     const float* __restrict__ ex_w,
                                                     ushort_t* __restrict__ attHi,
                                                     char* __restrict__ exq) {
    int gid = blockIdx.x * 256 + threadIdx.x;
    if (gid < 7680) {                                  // att bf16: 5 cb x 24 kb x 64 l
        int cb = gid / 1536;
        int rem = gid - cb * 1536;
        int l = rem & 63;
        int col = cb * 16 + (l & 15);
        int k = ((rem >> 6) << 5) + ((l >> 4) << 3);
        union { ushort_t u[8]; short8v v; } H;
        #pragma unroll
        for (int e = 0; e < 8; ++e) {
            int c = k + e;
            float f = (col < 72) ? att_w[(size_t)(col & 7) * 6912 + c * 9 + (col >> 3)] : 0.f;
            H.u[e] = f2bf_rne(f);
        }
        *(short8v*)&attHi[(size_t)gid * 8] = H.v;
    } else if (gid < 8448) {                           // ex int8: 12 kb x 64 l
        int g2 = gid - 7680;
        int l = g2 & 63;
        int col = l & 15;
        int k0 = ((g2 >> 6) << 6) + ((l >> 4) << 4);
        union { char c[16]; i32x4 v; } Q;
        #pragma unroll
        for (int e = 0; e < 16; ++e) {
            int k = k0 + e;
            float f = (col < 9) ? ex_w[k * 9 + col] : 0.f;
            Q.c[e] = q8(f, 1024.f);
        }
        *(i32x4*)&exq[(size_t)g2 * 16] = Q.v;
    }
}

// ---------------- qkv/proj weights -> bf16 frags ----------------
__global__ __launch_bounds__(256) void wgemm_split_kernel(const float* __restrict__ qkv_w,
                                                          const float* __restrict__ proj_w,
                                                          ushort_t* __restrict__ wqkvF,
                                                          ushort_t* __restrict__ wprojF) {
    int gid = blockIdx.x * 256 + threadIdx.x;
    const float* W; ushort_t* D; int g2;
    if (gid < 221184) { W = qkv_w; D = wqkvF; g2 = gid; }
    else { W = proj_w; D = wprojF; g2 = gid - 221184; }
    int cb = g2 / 1536;
    int rem = g2 - cb * 1536;
    int l = rem & 63;
    int col = cb * 16 + (l & 15);
    int k = ((rem >> 6) << 5) + ((l >> 4) << 3);
    union { ushort_t u[8]; short8v v; } H;
    #pragma unroll
    for (int e = 0; e < 8; ++e) H.u[e] = f2bf_rne(W[(size_t)col * 768 + k + e]);
    *(short8v*)&D[(size_t)g2 * 8] = H.v;
}

// ---------------- VQ: int8 MFMA, BM=64 BN=512 BK=64, dbuf + counted vmcnt ----
// grid (8, 196): g = code split (1024 codes, XCD-pinned), mt = 64-row tile
__global__ __launch_bounds__(256, 2) void vq_i8_kernel(const char* __restrict__ Aq,
                                                       const char* __restrict__ CBq,
                                                       const float* __restrict__ cnq,
                                                       float4* __restrict__ cand) {
    __shared__ __align__(16) char AqL[2][4096];
    __shared__ __align__(16) char BqL[2][32768];
    const int tid = threadIdx.x;
    const int l = tid & 63, w = tid >> 6;              // w = col quadrant 0..3
    const int g = blockIdx.x;
    const int mt = blockIdx.y;
    const int row0 = mt * 64;
    const int rg0 = mt * 4;

    float v1[4][4], v2[4][4]; int i1[4][4], i2[4][4];
    #pragma unroll
    for (int mf = 0; mf < 4; ++mf)
        #pragma unroll
        for (int rg = 0; rg < 4; ++rg) {
            v1[mf][rg] = INFINITY; v2[mf][rg] = INFINITY;
            i1[mf][rg] = 0x7fffffff; i2[mf][rg] = 0x7fffffff;
        }

    auto STAGE = [&](int buf, int u) {
        int ch = (u >= 12) ? 1 : 0;
        int st = u - ch * 12;
        int cbase = g * 64 + ch * 32;
        #pragma unroll
        for (int i = 0; i < 9; ++i) {
            int s = w * 9 + i;
            if (s < 4)
                gload_lds16(&Aq[(((size_t)(rg0 + s) * 12 + st) << 10) + l * 16],
                            &AqL[buf][s << 10]);
            else {
                int cb = s - 4;
                gload_lds16(&CBq[(((size_t)(cbase + cb) * 12 + st) << 10) + l * 16],
                            &BqL[buf][cb << 10]);
            }
        }
    };

    int cur = 0;
    STAGE(0, 0);
    __syncthreads();                                   // full drain once (prologue)

    #pragma unroll 1
    for (int ch = 0; ch < 2; ++ch) {
        i32x4 acc[4][8];
        #pragma unroll
        for (int mf = 0; mf < 4; ++mf)
            #pragma unroll
            for (int nf = 0; nf < 8; ++nf) acc[mf][nf] = (i32x4){0, 0, 0, 0};

        #pragma unroll 1
        for (int st = 0; st < 12; ++st) {
            int u = ch * 12 + st;
            if (u < 23) STAGE(cur ^ 1, u + 1);         // prefetch next stage
            i32x4 aq[4];
            #pragma unroll
            for (int mf = 0; mf < 4; ++mf)
                aq[mf] = *(const i32x4*)&AqL[cur][(mf << 10) + l * 16];
            #pragma unroll
            for (int nf = 0; nf < 8; ++nf) {
                i32x4 bq = *(const i32x4*)&BqL[cur][((w * 8 + nf) << 10) + l * 16];
                #pragma unroll
                for (int mf = 0; mf < 4; ++mf)
                    acc[mf][nf] = __builtin_amdgcn_mfma_i32_16x16x64_i8(aq[mf], bq, acc[mf][nf], 0, 0, 0);
            }
            // counted drain: wait only for the PREVIOUS buffer's loads (keep 9 in flight)
            asm volatile("s_waitcnt vmcnt(9)" ::: "memory");
            __builtin_amdgcn_sched_barrier(0);
            __builtin_amdgcn_s_barrier();
            __builtin_amdgcn_sched_barrier(0);
            cur ^= 1;
        }
        // chunk epilogue: d~ = 1024*(cn - 2 x.c); per-lane top-2 insert
        #pragma unroll
        for (int nf = 0; nf < 8; ++nf) {
            int code = g * 1024 + ch * 512 + w * 128 + nf * 16 + (l & 15);
            float cnv = cnq[code];
            #pragma unroll
            for (int mf = 0; mf < 4; ++mf)
                #pragma unroll
                for (int rg = 0; rg < 4; ++rg) {
                    float d = fmaf(-2.f, (float)acc[mf][nf][rg], cnv);
                    bool c1 = d < v1[mf][rg];
                    bool c2 = d < v2[mf][rg];
                    float nv2 = c1 ? v1[mf][rg] : (c2 ? d : v2[mf][rg]);
                    int   ni2 = c1 ? i1[mf][rg] : (c2 ? code : i2[mf][rg]);
                    v2[mf][rg] = nv2; i2[mf][rg] = ni2;
                    if (c1) { v1[mf][rg] = d; i1[mf][rg] = code; }
                }
        }
    }
    // cross-lane exact top-2 per row over the 16 col-lanes; write subset pair
    #pragma unroll
    for (int mf = 0; mf < 4; ++mf)
        #pragma unroll
        for (int rg = 0; rg < 4; ++rg) {
            float a1 = v1[mf][rg], a2 = v2[mf][rg];
            int b1 = i1[mf][rg], b2 = i2[mf][rg];
            #pragma unroll
            for (int off = 8; off >= 1; off >>= 1) {
                float w1 = __shfl_xor(a1, off, 64), w2 = __shfl_xor(a2, off, 64);
                int j1 = __shfl_xor(b1, off, 64), j2 = __shfl_xor(b2, off, 64);
                top2_merge(a1, b1, a2, b2, w1, j1, w2, j2);
            }
            if ((l & 15) == 0) {
                int row = row0 + mf * 16 + (l >> 4) * 4 + rg;
                cand[(size_t)row * 32 + g * 4 + w] =
                    make_float4(a1, __int_as_float(b1), a2, __int_as_float(b2));
            }
        }
}

// ---------------- rescore: exact top-4 of 32 subset-pairs, fp64 re-eval ------
__global__ __launch_bounds__(256) void rescore_kernel(const float4* __restrict__ cand,
                                                      const float* __restrict__ X,
                                                      const float* __restrict__ CB,
                                                      int* __restrict__ idx,
                                                      float* __restrict__ encOut) {
    int w = threadIdx.x >> 6, l = threadIdx.x & 63;
    int r = blockIdx.x * 4 + w;
    float a0, a1, a2, a3; int j0, j1, j2, j3;
    if (l < 32) {
        float4 c = cand[(size_t)r * 32 + l];
        a0 = c.x; j0 = __float_as_int(c.y);
        a1 = c.z; j1 = __float_as_int(c.w);
    } else { a0 = INFINITY; a1 = INFINITY; j0 = 0x7fffffff; j1 = 0x7fffffff; }
    a2 = INFINITY; a3 = INFINITY; j2 = 0x7fffffff; j3 = 0x7fffffff;
    #pragma unroll
    for (int off = 32; off >= 1; off >>= 1) {
        float b0 = __shfl_xor(a0, off, 64), b1 = __shfl_xor(a1, off, 64);
        float b2 = __shfl_xor(a2, off, 64), b3 = __shfl_xor(a3, off, 64);
        int p0 = __shfl_xor(j0, off, 64), p1 = __shfl_xor(j1, off, 64);
        int p2 = __shfl_xor(j2, off, 64), p3 = __shfl_xor(j3, off, 64);
        pickmin(a0, j0, b3, p3); pickmin(a1, j1, b2, p2);
        pickmin(a2, j2, b1, p1); pickmin(a3, j3, b0, p0);
        ce4(a0, j0, a2, j2); ce4(a1, j1, a3, j3);
        ce4(a0, j0, a1, j1); ce4(a2, j2, a3, j3);
    }
    double dot0 = 0, dot1 = 0, dot2 = 0, dot3 = 0;
    double nn0 = 0, nn1 = 0, nn2 = 0, nn3 = 0;
    const float* xr = X + (size_t)r * C_;
    #pragma unroll
    for (int jj = 0; jj < 12; ++jj) {
        int c = l * 12 + jj;
        double x = (double)xr[c];
        double c0 = (double)CB[(size_t)j0 * C_ + c]; dot0 += x * c0; nn0 += c0 * c0;
        double c1 = (double)CB[(size_t)j1 * C_ + c]; dot1 += x * c1; nn1 += c1 * c1;
        double c2 = (double)CB[(size_t)j2 * C_ + c]; dot2 += x * c2; nn2 += c2 * c2;
        double c3 = (double)CB[(size_t)j3 * C_ + c]; dot3 += x * c3; nn3 += c3 * c3;
    }
    #pragma unroll
    for (int off = 32; off >= 1; off >>= 1) {
        dot0 += __shfl_xor(dot0, off, 64); dot1 += __shfl_xor(dot1, off, 64);
        dot2 += __shfl_xor(dot2, off, 64); dot3 += __shfl_xor(dot3, off, 64);
        nn0 += __shfl_xor(nn0, off, 64); nn1 += __shfl_xor(nn1, off, 64);
        nn2 += __shfl_xor(nn2, off, 64); nn3 += __shfl_xor(nn3, off, 64);
    }
    if (l == 0) {
        double d0 = nn0 - 2.0 * dot0, d1 = nn1 - 2.0 * dot1;
        double d2 = nn2 - 2.0 * dot2, d3 = nn3 - 2.0 * dot3;
        double best = d0; int bi = j0;
        if (d1 < best || (d1 == best && j1 < bi)) { best = d1; bi = j1; }
        if (d2 < best || (d2 == best && j2 < bi)) { best = d2; bi = j2; }
        if (d3 < best || (d3 == best && j3 < bi)) { best = d3; bi = j3; }
        idx[r] = bi;
        encOut[r] = (float)bi;
    }
}

// ---------------- motion conv GEMM (int8): XW[12544][16] ----------------
__global__ __launch_bounds__(256) void convgemm_i8_kernel(const char* __restrict__ Aq,
                                                          const char* __restrict__ Bq,
                                                          float* __restrict__ out) {
    __shared__ __align__(16) char AqL[8 * 1024];
    __shared__ __align__(16) char BqL[1024];
    const int tid = threadIdx.x;
    const int l = tid & 63, w = tid >> 6;
    const int rg0 = blockIdx.x * 8, row0 = blockIdx.x * 128;
    i32x4 acc[2];
    acc[0] = (i32x4){0, 0, 0, 0}; acc[1] = (i32x4){0, 0, 0, 0};
    #pragma unroll 1
    for (int st = 0; st < 12; ++st) {
        __syncthreads();
        #pragma unroll
        for (int i = 0; i < 3; ++i) {
            int s = w * 3 + i;
            if (s < 8)
                gload_lds16(&Aq[(((size_t)(rg0 + s) * 12 + st) << 10) + l * 16], &AqL[s << 10]);
            else if (s == 8)
                gload_lds16(&Bq[((size_t)st << 10) + l * 16], &BqL[0]);
        }
        __syncthreads();
        i32x4 bq = *(const i32x4*)&BqL[l * 16];
        #pragma unroll
        for (int mf = 0; mf < 2; ++mf) {
            i32x4 aq = *(const i32x4*)&AqL[((w * 2 + mf) << 10) + l * 16];
            acc[mf] = __builtin_amdgcn_mfma_i32_16x16x64_i8(aq, bq, acc[mf], 0, 0, 0);
        }
    }
    #pragma unroll
    for (int mf = 0; mf < 2; ++mf)
        #pragma unroll
        for (int rg = 0; rg < 4; ++rg) {
            int row = row0 + w * 32 + mf * 16 + (l >> 4) * 4 + rg;
            out[(size_t)row * 16 + (l & 15)] = (float)acc[mf][rg] * (1.f / 32768.f);
        }
}

// ---------------- bf16 conv GEMM (region mask): out[12544][NF*16] -----------
template<int NF>
__global__ __launch_bounds__(256) void convgemm_kernel(const ushort_t* __restrict__ Ahi_g,
                                                       const ushort_t* __restrict__ Bhi_g,
                                                       float* __restrict__ out) {
    __shared__ __align__(16) ushort_t AhL[16 * 512];
    __shared__ __align__(16) ushort_t BhL[NF * 2 * 512];
    const int TOT = 16 + 2 * NF;
    const int PW = (TOT + 3) >> 2;
    const int tid = threadIdx.x;
    const int l = tid & 63, w = tid >> 6;
    const int rg0 = blockIdx.x * 8;
    const int row0 = blockIdx.x * 128;
    f32x4 acc[2][NF];
    #pragma unroll
    for (int mf = 0; mf < 2; ++mf)
        #pragma unroll
        for (int nf = 0; nf < NF; ++nf) acc[mf][nf] = (f32x4){0.f, 0.f, 0.f, 0.f};
    #pragma unroll 1
    for (int st = 0; st < 12; ++st) {
        __syncthreads();
        #pragma unroll
        for (int i = 0; i < PW; ++i) {
            int s = w * PW + i;
            if (s < 16) {
                int rb = s >> 1, kb = s & 1;
                gload_lds16(&Ahi_g[(((size_t)(rg0 + rb) * 24 + st * 2 + kb) << 9) + l * 8], &AhL[s << 9]);
            } else if (s < TOT) {
                int t2 = s - 16;
                int cb = t2 >> 1, kb = t2 & 1;
                gload_lds16(&Bhi_g[(((size_t)cb * 24 + st * 2 + kb) << 9) + l * 8], &BhL[t2 << 9]);
            }
        }
        __syncthreads();
        #pragma unroll
        for (int kf = 0; kf < 2; ++kf) {
            short8v ah[2];
            #pragma unroll
            for (int mf = 0; mf < 2; ++mf)
                ah[mf] = *(const short8v*)&AhL[(((w * 2 + mf) * 2 + kf) << 9) + l * 8];
            #pragma unroll
            for (int nf = 0; nf < NF; ++nf) {
                short8v bh = *(const short8v*)&BhL[((nf * 2 + kf) << 9) + l * 8];
                #pragma unroll
                for (int mf = 0; mf < 2; ++mf)
                    acc[mf][nf] = __builtin_amdgcn_mfma_f32_16x16x32_bf16(ah[mf], bh, acc[mf][nf], 0, 0, 0);
            }
        }
    }
    #pragma unroll
    for (int mf = 0; mf < 2; ++mf)
        #pragma unroll
        for (int nf = 0; nf < NF; ++nf)
            #pragma unroll
            for (int rg = 0; rg < 4; ++rg) {
                int row = row0 + w * 32 + mf * 16 + (l >> 4) * 4 + rg;
                out[(size_t)row * (NF * 16) + nf * 16 + (l & 15)] = acc[mf][nf][rg];
            }
}

// ---------------- generic frag-GEMM with bias: out[M][N] fp32 ----------------
template<int NF>
__global__ __launch_bounds__(256) void gemm_frag_kernel(const ushort_t* __restrict__ Af,
                                                        const ushort_t* __restrict__ Bf,
                                                        const float* __restrict__ bias,
                                                        float* __restrict__ out, int N) {
    __shared__ __align__(16) ushort_t AhL[16 * 512];
    __shared__ __align__(16) ushort_t BhL[2 * NF * 512];
    const int TOT = 16 + 2 * NF;
    const int PW = (TOT + 3) >> 2;
    const int tid = threadIdx.x;
    const int l = tid & 63, w = tid >> 6;
    const int rg0 = blockIdx.x * 8, row0 = blockIdx.x * 128;
    const int cb0 = blockIdx.y * NF;
    f32x4 acc[2][NF];
    #pragma unroll
    for (int mf = 0; mf < 2; ++mf)
        #pragma unroll
        for (int nf = 0; nf < NF; ++nf) acc[mf][nf] = (f32x4){0.f, 0.f, 0.f, 0.f};
    #pragma unroll 1
    for (int st = 0; st < 12; ++st) {
        __syncthreads();
        #pragma unroll
        for (int i = 0; i < PW; ++i) {
            int s = w * PW + i;
            if (s < 16) {
                int rb = s >> 1, kb = s & 1;
                gload_lds16(&Af[(((size_t)(rg0 + rb) * 24 + st * 2 + kb) << 9) + l * 8], &AhL[s << 9]);
            } else if (s < TOT) {
                int t2 = s - 16;
                int cb = t2 >> 1, kb = t2 & 1;
                gload_lds16(&Bf[(((size_t)(cb0 + cb) * 24 + st * 2 + kb) << 9) + l * 8], &BhL[t2 << 9]);
            }
        }
        __syncthreads();
        #pragma unroll
        for (int kf = 0; kf < 2; ++kf) {
            short8v ah[2];
            #pragma unroll
            for (int mf = 0; mf < 2; ++mf)
                ah[mf] = *(const short8v*)&AhL[(((w * 2 + mf) * 2 + kf) << 9) + l * 8];
            #pragma unroll
            for (int nf = 0; nf < NF; ++nf) {
                short8v bh = *(const short8v*)&BhL[((nf * 2 + kf) << 9) + l * 8];
                #pragma unroll
                for (int mf = 0; mf < 2; ++mf)
                    acc[mf][nf] = __builtin_amdgcn_mfma_f32_16x16x32_bf16(ah[mf], bh, acc[mf][nf], 0, 0, 0);
            }
        }
    }
    #pragma unroll
    for (int mf = 0; mf < 2; ++mf)
        #pragma unroll
        for (int nf = 0; nf < NF; ++nf) {
            int col = (cb0 + nf) * 16 + (l & 15);
            float bv = bias[col];
            #pragma unroll
            for (int rg = 0; rg < 4; ++rg) {
                int row = row0 + w * 32 + mf * 16 + (l >> 4) * 4 + rg;
                out[(size_t)row * N + col] = acc[mf][nf][rg] + bv;
            }
        }
}

// ---------------- mm finish: shifted-add + frame diff + softmax --------------
__global__ __launch_bounds__(256) void mm_finish_kernel(const float* __restrict__ XW,
                                                        const float* __restrict__ ex_b,
                                                        float* __restrict__ sm) {
    int b = blockIdx.x, t = threadIdx.x;
    float val = -INFINITY;
    if (t < L_) {
        if ((b & 3) == 0) val = ex_b[0];
        else {
            int yy = t / HW_, xx = t - (t / HW_) * HW_;
            float acc = 0.f;
            #pragma unroll
            for (int dy = 0; dy < 3; ++dy) {
                int sy = yy + dy - 1; if (sy < 0 || sy >= HW_) continue;
                #pragma unroll
                for (int dx = 0; dx < 3; ++dx) {
                    int sx = xx + dx - 1; if (sx < 0 || sx >= HW_) continue;
                    int q = sy * HW_ + sx, tap = dy * 3 + dx;
                    acc += XW[((size_t)b * L_ + q) * 16 + tap]
                         - XW[((size_t)(b - 1) * L_ + q) * 16 + tap];
                }
            }
            val = acc + ex_b[0];
        }
    }
    __shared__ float red[4];
    float mw = wave_reduce_max(val);
    if ((t & 63) == 0) red[t >> 6] = mw;
    __syncthreads();
    float mx = fmaxf(fmaxf(red[0], red[1]), fmaxf(red[2], red[3]));
    float e = (t < L_) ? expf(val - mx) : 0.f;
    __syncthreads();
    float sw = wave_reduce_sum(e);
    if ((t & 63) == 0) red[t >> 6] = sw;
    __syncthreads();
    float s = red[0] + red[1] + red[2] + red[3];
    if (t < L_) sm[b * L_ + t] = e / s;
}

// ---------------- vqf -> fragment-linear bf16 ----------------
__global__ __launch_bounds__(256) void vqf_split_kernel(const float* __restrict__ X,
                                                        const float* __restrict__ CB,
                                                        const int* __restrict__ idx,
                                                        const float* __restrict__ sm,
                                                        ushort_t* __restrict__ Vhi) {
    const int rg = blockIdx.x, t = threadIdx.x;
    #pragma unroll
    for (int i = 0; i < 6; ++i) {
        int s = t + i * 256;
        int kb = s >> 6, l = s & 63;
        int row = rg * 16 + (l & 15);
        int k = kb * 32 + ((l >> 4) << 3);
        int kidx = idx[row];
        float sc = sm[row];
        const float* xp = &X[(size_t)row * C_ + k];
        const float* cp = &CB[(size_t)kidx * C_ + k];
        union { ushort_t u[8]; short8v v; } H;
        #pragma unroll
        for (int e = 0; e < 8; ++e) H.u[e] = f2bf_rne(cp[e] + xp[e] * sc);
        *(short8v*)&Vhi[((size_t)rg * 1536 + s) * 8] = H.v;
    }
}

// ---------------- rm finish: shifted-add of OUTC + bias ----------------
__global__ __launch_bounds__(256) void rm_finish_kernel(const float* __restrict__ OUTC,
                                                        const float* __restrict__ att_b,
                                                        float* __restrict__ rmOut) {
    int gid = blockIdx.x * 256 + threadIdx.x;
    if (gid >= B_ * R_ * L_) return;
    int b = gid / (R_ * L_);
    int rem = gid - b * (R_ * L_);
    int r = rem / L_, p = rem - r * L_;
    int yy = p / HW_, xx = p - yy * HW_;
    float acc = att_b[r];
    #pragma unroll
    for (int dy = 0; dy < 3; ++dy) {
        int sy = yy + dy - 1; if (sy < 0 || sy >= HW_) continue;
        #pragma unroll
        for (int dx = 0; dx < 3; ++dx) {
            int sx = xx + dx - 1; if (sx < 0 || sx >= HW_) continue;
            int q = sy * HW_ + sx, tap = dy * 3 + dx;
            acc += OUTC[((size_t)b * L_ + q) * 80 + tap * 8 + r];
        }
    }
    rmOut[gid] = acc;
}

// ---------------- regions einsum from Vhi -> seq frags (bf16) ----------------
__global__ __launch_bounds__(256) void regions_kernel(const ushort_t* __restrict__ Vhi,
                                                      const float* __restrict__ rm,
                                                      ushort_t* __restrict__ seqF) {
    int b = blockIdx.x, cg = blockIdx.y, t = threadIdx.x;
    __shared__ float rms[R_ * L_];
    for (int i = t; i < R_ * L_; i += 256) rms[i] = rm[(size_t)b * R_ * L_ + i];
    __syncthreads();
    const float inv = 1.f / 196.f;
    int c = cg * 256 + t;
    int kb = c >> 5, q = (c >> 3) & 3, e = c & 7;
    float acc[R_] = {};
    for (int p = 0; p < L_; ++p) {
        int row = b * L_ + p;
        int rg = row >> 4, rr = row & 15;
        size_t a = (((size_t)rg * 24 + kb) * 64 + q * 16 + rr) * 8 + e;
        float x = bf2f(Vhi[a]);
        #pragma unroll
        for (int r = 0; r < R_; ++r) acc[r] += x * rms[r * L_ + p];
    }
    #pragma unroll
    for (int r = 0; r < R_; ++r) {
        int row = b * 8 + r;
        int rg2 = row >> 4, rr = row & 15;
        seqF[(((size_t)rg2 * 24 + kb) * 64 + q * 16 + rr) * 8 + e] = f2bf_rne(acc[r] * inv);
    }
}

// ---------------- per-(batch,head) attention -> frag-linear bf16 out ---------
__global__ __launch_bounds__(256) void attn_kernel(const float* __restrict__ qkv,
                                                   ushort_t* __restrict__ outF) {
    int bp = blockIdx.x, h = blockIdx.y;
    __shared__ float qs[NT_][DH_], ks[NT_][DH_], vs[NT_][DH_];
    __shared__ float sc[NT_][NT_ + 1];
    int tid = threadIdx.x;
    for (int e = tid; e < NT_ * DH_; e += 256) {
        int n = e / DH_, d = e - n * DH_;
        size_t base = ((size_t)(bp * NT_ + n)) * 2304 + h * DH_ + d;
        qs[n][d] = qkv[base];
        ks[n][d] = qkv[base + 768];
        vs[n][d] = qkv[base + 1536];
    }
    __syncthreads();
    const float scale = 1.0f / sqrtf((float)DH_);
    for (int e = tid; e < NT_ * NT_; e += 256) {
        int n = e >> 5, m = e & 31;
        float s = 0.f;
        #pragma unroll 8
        for (int d = 0; d < DH_; ++d) s += qs[n][d] * ks[m][d];
        sc[n][m] = s * scale;
    }
    __syncthreads();
    if (tid < NT_) {
        float mx = -INFINITY;
        #pragma unroll
        for (int m = 0; m < NT_; ++m) mx = fmaxf(mx, sc[tid][m]);
        float sum = 0.f;
        #pragma unroll
        for (int m = 0; m < NT_; ++m) { float e2 = expf(sc[tid][m] - mx); sc[tid][m] = e2; sum += e2; }
        float inv = 1.f / sum;
        #pragma unroll
        for (int m = 0; m < NT_; ++m) sc[tid][m] *= inv;
    }
    __syncthreads();
    for (int e = tid; e < NT_ * DH_; e += 256) {
        int n = e / DH_, d = e - n * DH_;
        float o = 0.f;
        #pragma unroll
        for (int m = 0; m < NT_; ++m) o += sc[n][m] * vs[m][d];
        int row = bp * NT_ + n, c = h * DH_ + d;
        outF[(((size_t)(row >> 4) * 24 + (c >> 5)) * 64 + ((c >> 3) & 3) * 16 + (row & 15)) * 8 + (c & 7)]
            = f2bf_rne(o);
    }
}

// ---------------- launch ----------------
extern "C" void kernel_launch(void* const* d_in, const int* in_sizes, int n_in,
                              void* d_out, int out_size, void* d_ws, size_t ws_size,
                              hipStream_t stream) {
    const float* in_feas  = (const float*)d_in[0];
    const float* codebook = (const float*)d_in[2];
    const float* att_w    = (const float*)d_in[3];
    const float* att_b    = (const float*)d_in[4];
    const float* ex_w     = (const float*)d_in[5];
    const float* ex_b     = (const float*)d_in[6];
    const float* qkv_w    = (const float*)d_in[7];
    const float* qkv_b    = (const float*)d_in[8];
    const float* proj_w   = (const float*)d_in[9];
    const float* proj_b   = (const float*)d_in[10];

    float* out    = (float*)d_out;
    float* outVd  = out;
    float* outEnc = out + 393216;
    float* outRm  = out + 393216 + 12544;

    float* ws = (float*)d_ws;
    // flat layout, no overlays (~57.7 MB)
    float*    cnq    = ws + 0;                          // 8,192
    float4*   cand   = (float4*)(ws + 8192);            // 1,605,632 fl
    char*     CBq    = (char*)(ws + 1613824);           // 1,572,864 fl
    char*     Aq     = (char*)(ws + 3186688);           // 2,408,448 fl
    ushort_t* attHi  = (ushort_t*)(ws + 5595136);       // 30,720 fl
    char*     exq    = (char*)(ws + 5625856);           // 3,072 fl
    ushort_t* wqkvF  = (ushort_t*)(ws + 5628928);       // 884,736 fl
    ushort_t* wprojF = (ushort_t*)(ws + 6513664);       // 294,912 fl
    int*      idx    = (int*)(ws + 6808576);            // 12,544
    float*    XW     = ws + 6821120;                    // 200,704
    float*    sm     = ws + 7021824;                    // 12,544
    ushort_t* Vhi    = (ushort_t*)(ws + 7034368);       // 4,816,896 fl
    float*    OUTC   = ws + 11851264;                   // 1,003,520
    ushort_t* seqF   = (ushort_t*)(ws + 12854784);      // 196,608 fl
    float*    qkvb   = ws + 13051392;                   // 1,179,648
    ushort_t* attnbF = (ushort_t*)(ws + 14231040);      // 196,608 fl -> 14,427,648

    hipLaunchKernelGGL(cbq_kernel, dim3(512), dim3(256), 0, stream, codebook, CBq, cnq);
    hipLaunchKernelGGL(aq_kernel, dim3(784), dim3(256), 0, stream, in_feas, Aq);
    hipLaunchKernelGGL(wsplit_kernel, dim3(33), dim3(256), 0, stream, att_w, ex_w, attHi, exq);
    hipLaunchKernelGGL(wgemm_split_kernel, dim3(1152), dim3(256), 0, stream,
                       qkv_w, proj_w, wqkvF, wprojF);
    hipLaunchKernelGGL(vq_i8_kernel, dim3(8, 196), dim3(256), 0, stream, Aq, CBq, cnq, cand);
    hipLaunchKernelGGL(convgemm_i8_kernel, dim3(98), dim3(256), 0, stream, Aq, exq, XW);
    hipLaunchKernelGGL(rescore_kernel, dim3(M_ / 4), dim3(256), 0, stream,
                       cand, in_feas, codebook, idx, outEnc);
    hipLaunchKernelGGL(mm_finish_kernel, dim3(B_), dim3(256), 0, stream, XW, ex_b, sm);
    hipLaunchKernelGGL(vqf_split_kernel, dim3(784), dim3(256), 0, stream,
                       in_feas, codebook, idx, sm, Vhi);
    hipLaunchKernelGGL((convgemm_kernel<5>), dim3(98), dim3(256), 0, stream, Vhi, attHi, OUTC);
    hipLaunchKernelGGL(rm_finish_kernel, dim3(392), dim3(256), 0, stream, OUTC, att_b, outRm);
    hipLaunchKernelGGL(regions_kernel, dim3(B_, 3), dim3(256), 0, stream, Vhi, outRm, seqF);
    hipLaunchKernelGGL((gemm_frag_kernel<8>), dim3(4, 18), dim3(256), 0, stream,
                       seqF, wqkvF, qkv_b, qkvb, 2304);
    hipLaunchKernelGGL(attn_kernel, dim3(BP_, NH_), dim3(256), 0, stream, qkvb, attnbF);
    hipLaunchKernelGGL((gemm_frag_kernel<8>), dim3(4, 6), dim3(256), 0, stream,
                       attnbF, wprojF, proj_b, outVd, 768);
}

// Round 10
// 344.909 us; speedup vs baseline: 1.0019x; 1.0019x over previous
//
#include <hip/hip_runtime.h>
#include <math.h>

#define B_   64
#define L_   196
#define C_   768
#define K_   8192
#define R_   8
#define HW_  14
#define M_   (B_*L_)     // 12544
#define NH_  8
#define DH_  96
#define BP_  16
#define NT_  32

typedef unsigned short ushort_t;
typedef __attribute__((ext_vector_type(8))) short short8v;   // 8 bf16 (4 VGPR)
typedef __attribute__((ext_vector_type(4))) float f32x4;     // MFMA 16x16 f32 acc
typedef __attribute__((ext_vector_type(4))) int   i32x4;     // MFMA i8 operands/acc

// ---------------- utilities ----------------
__device__ inline float wave_reduce_sum(float v) {
    #pragma unroll
    for (int o = 32; o >= 1; o >>= 1) v += __shfl_xor(v, o, 64);
    return v;
}
__device__ inline float wave_reduce_max(float v) {
    #pragma unroll
    for (int o = 32; o >= 1; o >>= 1) v = fmaxf(v, __shfl_xor(v, o, 64));
    return v;
}

__device__ inline ushort_t f2bf_rne(float f) {
    unsigned u = __float_as_uint(f);
    unsigned r = u + 0x7fffu + ((u >> 16) & 1u);
    return (ushort_t)(r >> 16);
}
__device__ inline float bf2f(ushort_t h) { return __uint_as_float(((unsigned)h) << 16); }

__device__ inline char q8(float f, float s) {
    int q = __float2int_rn(f * s);
    return (char)(q < -127 ? -127 : (q > 127 ? 127 : q));
}

__device__ inline void gload_lds16(const void* gsrc, void* ldst) {
    __builtin_amdgcn_global_load_lds(
        (const __attribute__((address_space(1))) unsigned int*)gsrc,
        (__attribute__((address_space(3))) unsigned int*)ldst, 16, 0, 0);
}

// merge two sorted pairs -> sorted top-2 of union (lowest-index tie-break)
__device__ inline void top2_merge(float& v1, int& i1, float& v2, int& i2,
                                  float w1, int j1, float w2, int j2) {
    bool fw = (v1 < w1) || (v1 == w1 && i1 <= j1);
    float a1 = fw ? v1 : w1;  int ai1 = fw ? i1 : j1;
    float lb = fw ? w1 : v1;  int lbi = fw ? j1 : i1;
    float wsv = fw ? v2 : w2; int wsi = fw ? i2 : j2;
    bool sb = (lb < wsv) || (lb == wsv && lbi < wsi);
    v1 = a1; i1 = ai1;
    v2 = sb ? lb : wsv; i2 = sb ? lbi : wsi;
}

__device__ inline void ce4(float& v0, int& j0, float& v1, int& j1) {
    bool sw = (v1 < v0) || (v1 == v0 && j1 < j0);
    float tv = sw ? v1 : v0, uv = sw ? v0 : v1;
    int tj = sw ? j1 : j0, uj = sw ? j0 : j1;
    v0 = tv; j0 = tj; v1 = uv; j1 = uj;
}
__device__ inline void pickmin(float& v, int& j, float bv, int bj) {
    if (bv < v || (bv == v && bj < j)) { v = bv; j = bj; }
}

// ---------------- codebook -> int8 frags + norms (fused) ----------------
// CBq layout: [cb_g(512)][kb(12)][l(64)][e(16)] bytes; code=cb_g*16+(l&15), k=kb*64+(l>>4)*16+e
__global__ __launch_bounds__(256) void cbq_kernel(const float* __restrict__ CB,
                                                  char* __restrict__ CBq,
                                                  float* __restrict__ cnq) {
    __shared__ float xs[16 * 776];
    const int t = threadIdx.x;
    const int blk = blockIdx.x;
    const float4* src = (const float4*)(CB + (size_t)blk * 16 * C_);
    #pragma unroll
    for (int i = 0; i < 12; ++i) {
        int idx4 = t + i * 256;
        int r = idx4 / 192, c4 = idx4 - r * 192;
        ((float4*)(xs + r * 776))[c4] = src[idx4];
    }
    __syncthreads();
    #pragma unroll
    for (int i = 0; i < 3; ++i) {
        int s = t + i * 256;
        int kb = s >> 6, l = s & 63;
        int row = l & 15;
        int k0 = kb * 64 + ((l >> 4) << 4);
        union { char c[16]; i32x4 v; } Q;
        #pragma unroll
        for (int e = 0; e < 16; ++e) Q.c[e] = q8(xs[row * 776 + k0 + e], 32.f);
        *(i32x4*)&CBq[(((size_t)blk * 12 + kb) << 10) + l * 16] = Q.v;
    }
    // norms: thread t -> row t&15, chunk t>>4 (48 elems)
    int row = t & 15, chunk = t >> 4;
    float sum = 0.f;
    #pragma unroll
    for (int j = 0; j < 48; ++j) { float v = xs[row * 776 + chunk * 48 + j]; sum += v * v; }
    sum += __shfl_xor(sum, 16, 64);
    sum += __shfl_xor(sum, 32, 64);
    __shared__ float red[4][16];
    if ((t & 63) < 16) red[t >> 6][t & 15] = sum;
    __syncthreads();
    if (t < 16) cnq[blk * 16 + t] = (red[0][t] + red[1][t] + red[2][t] + red[3][t]) * 1024.f;
}

// ---------------- A -> int8 frags ----------------
__global__ __launch_bounds__(256) void aq_kernel(const float* __restrict__ X,
                                                 char* __restrict__ Aq) {
    __shared__ float xs[16 * 776];
    const int t = threadIdx.x;
    const int rg = blockIdx.x;
    const float4* src = (const float4*)(X + (size_t)rg * 16 * C_);
    #pragma unroll
    for (int i = 0; i < 12; ++i) {
        int idx4 = t + i * 256;
        int r = idx4 / 192, c4 = idx4 - r * 192;
        ((float4*)(xs + r * 776))[c4] = src[idx4];
    }
    __syncthreads();
    #pragma unroll
    for (int i = 0; i < 3; ++i) {
        int s = t + i * 256;
        int kb = s >> 6, l = s & 63;
        int row = l & 15;
        int k0 = kb * 64 + ((l >> 4) << 4);
        union { char c[16]; i32x4 v; } Q;
        #pragma unroll
        for (int e = 0; e < 16; ++e) Q.c[e] = q8(xs[row * 776 + k0 + e], 32.f);
        *(i32x4*)&Aq[(((size_t)rg * 12 + kb) << 10) + l * 16] = Q.v;
    }
}

// ---------------- conv weights: att bf16 frags + ex int8 frags ----------------
__global__ __launch_bounds__(256) void wsplit_kernel(const float* __restrict__ att_w,
                                                     const float* __restrict__ ex_w,
                                                     ushort_t* __restrict__ attHi,
                                                     char* __restrict__ exq) {
    int gid = blockIdx.x * 256 + threadIdx.x;
    if (gid < 7680) {                                  // att bf16: 5 cb x 24 kb x 64 l
        int cb = gid / 1536;
        int rem = gid - cb * 1536;
        int l = rem & 63;
        int col = cb * 16 + (l & 15);
        int k = ((rem >> 6) << 5) + ((l >> 4) << 3);
        union { ushort_t u[8]; short8v v; } H;
        #pragma unroll
        for (int e = 0; e < 8; ++e) {
            int c = k + e;
            float f = (col < 72) ? att_w[(size_t)(col & 7) * 6912 + c * 9 + (col >> 3)] : 0.f;
            H.u[e] = f2bf_rne(f);
        }
        *(short8v*)&attHi[(size_t)gid * 8] = H.v;
    } else if (gid < 8448) {                           // ex int8: 12 kb x 64 l
        int g2 = gid - 7680;
        int l = g2 & 63;
        int col = l & 15;
        int k0 = ((g2 >> 6) << 6) + ((l >> 4) << 4);
        union { char c[16]; i32x4 v; } Q;
        #pragma unroll
        for (int e = 0; e < 16; ++e) {
            int k = k0 + e;
            float f = (col < 9) ? ex_w[k * 9 + col] : 0.f;
            Q.c[e] = q8(f, 1024.f);
        }
        *(i32x4*)&exq[(size_t)g2 * 16] = Q.v;
    }
}

// ---------------- qkv/proj weights -> bf16 frags ----------------
__global__ __launch_bounds__(256) void wgemm_split_kernel(const float* __restrict__ qkv_w,
                                                          const float* __restrict__ proj_w,
                                                          ushort_t* __restrict__ wqkvF,
                                                          ushort_t* __restrict__ wprojF) {
    int gid = blockIdx.x * 256 + threadIdx.x;
    const float* W; ushort_t* D; int g2;
    if (gid < 221184) { W = qkv_w; D = wqkvF; g2 = gid; }
    else { W = proj_w; D = wprojF; g2 = gid - 221184; }
    int cb = g2 / 1536;
    int rem = g2 - cb * 1536;
    int l = rem & 63;
    int col = cb * 16 + (l & 15);
    int k = ((rem >> 6) << 5) + ((l >> 4) << 3);
    union { ushort_t u[8]; short8v v; } H;
    #pragma unroll
    for (int e = 0; e < 8; ++e) H.u[e] = f2bf_rne(W[(size_t)col * 768 + k + e]);
    *(short8v*)&D[(size_t)g2 * 8] = H.v;
}

// ---------------- VQ: int8 MFMA, BM=64 BN=512 BK=64, dbuf + counted vmcnt ----
// grid (8, 196): g = code split (1024 codes, XCD-pinned), mt = 64-row tile
__global__ __launch_bounds__(256, 2) void vq_i8_kernel(const char* __restrict__ Aq,
                                                       const char* __restrict__ CBq,
                                                       const float* __restrict__ cnq,
                                                       float4* __restrict__ cand) {
    __shared__ __align__(16) char AqL[2][4096];
    __shared__ __align__(16) char BqL[2][32768];
    const int tid = threadIdx.x;
    const int l = tid & 63, w = tid >> 6;              // w = col quadrant 0..3
    const int g = blockIdx.x;
    const int mt = blockIdx.y;
    const int row0 = mt * 64;
    const int rg0 = mt * 4;

    float v1[4][4], v2[4][4]; int i1[4][4], i2[4][4];
    #pragma unroll
    for (int mf = 0; mf < 4; ++mf)
        #pragma unroll
        for (int rg = 0; rg < 4; ++rg) {
            v1[mf][rg] = INFINITY; v2[mf][rg] = INFINITY;
            i1[mf][rg] = 0x7fffffff; i2[mf][rg] = 0x7fffffff;
        }

    auto STAGE = [&](int buf, int u) {
        int ch = (u >= 12) ? 1 : 0;
        int st = u - ch * 12;
        int cbase = g * 64 + ch * 32;
        #pragma unroll
        for (int i = 0; i < 9; ++i) {
            int s = w * 9 + i;
            if (s < 4)
                gload_lds16(&Aq[(((size_t)(rg0 + s) * 12 + st) << 10) + l * 16],
                            &AqL[buf][s << 10]);
            else {
                int cb = s - 4;
                gload_lds16(&CBq[(((size_t)(cbase + cb) * 12 + st) << 10) + l * 16],
                            &BqL[buf][cb << 10]);
            }
        }
    };

    int cur = 0;
    STAGE(0, 0);
    __syncthreads();                                   // full drain once (prologue)

    #pragma unroll 1
    for (int ch = 0; ch < 2; ++ch) {
        i32x4 acc[4][8];
        #pragma unroll
        for (int mf = 0; mf < 4; ++mf)
            #pragma unroll
            for (int nf = 0; nf < 8; ++nf) acc[mf][nf] = (i32x4){0, 0, 0, 0};

        #pragma unroll 1
        for (int st = 0; st < 12; ++st) {
            int u = ch * 12 + st;
            if (u < 23) STAGE(cur ^ 1, u + 1);         // prefetch next stage
            i32x4 aq[4];
            #pragma unroll
            for (int mf = 0; mf < 4; ++mf)
                aq[mf] = *(const i32x4*)&AqL[cur][(mf << 10) + l * 16];
            #pragma unroll
            for (int nf = 0; nf < 8; ++nf) {
                i32x4 bq = *(const i32x4*)&BqL[cur][((w * 8 + nf) << 10) + l * 16];
                #pragma unroll
                for (int mf = 0; mf < 4; ++mf)
                    acc[mf][nf] = __builtin_amdgcn_mfma_i32_16x16x64_i8(aq[mf], bq, acc[mf][nf], 0, 0, 0);
            }
            // counted drain: wait only for the PREVIOUS buffer's loads (keep 9 in flight)
            asm volatile("s_waitcnt vmcnt(9)" ::: "memory");
            __builtin_amdgcn_sched_barrier(0);
            __builtin_amdgcn_s_barrier();
            __builtin_amdgcn_sched_barrier(0);
            cur ^= 1;
        }
        // chunk epilogue: d~ = 1024*(cn - 2 x.c); per-lane top-2 insert
        #pragma unroll
        for (int nf = 0; nf < 8; ++nf) {
            int code = g * 1024 + ch * 512 + w * 128 + nf * 16 + (l & 15);
            float cnv = cnq[code];
            #pragma unroll
            for (int mf = 0; mf < 4; ++mf)
                #pragma unroll
                for (int rg = 0; rg < 4; ++rg) {
                    float d = fmaf(-2.f, (float)acc[mf][nf][rg], cnv);
                    bool c1 = d < v1[mf][rg];
                    bool c2 = d < v2[mf][rg];
                    float nv2 = c1 ? v1[mf][rg] : (c2 ? d : v2[mf][rg]);
                    int   ni2 = c1 ? i1[mf][rg] : (c2 ? code : i2[mf][rg]);
                    v2[mf][rg] = nv2; i2[mf][rg] = ni2;
                    if (c1) { v1[mf][rg] = d; i1[mf][rg] = code; }
                }
        }
    }
    // cross-lane exact top-2 per row over the 16 col-lanes; write subset pair
    #pragma unroll
    for (int mf = 0; mf < 4; ++mf)
        #pragma unroll
        for (int rg = 0; rg < 4; ++rg) {
            float a1 = v1[mf][rg], a2 = v2[mf][rg];
            int b1 = i1[mf][rg], b2 = i2[mf][rg];
            #pragma unroll
            for (int off = 8; off >= 1; off >>= 1) {
                float w1 = __shfl_xor(a1, off, 64), w2 = __shfl_xor(a2, off, 64);
                int j1 = __shfl_xor(b1, off, 64), j2 = __shfl_xor(b2, off, 64);
                top2_merge(a1, b1, a2, b2, w1, j1, w2, j2);
            }
            if ((l & 15) == 0) {
                int row = row0 + mf * 16 + (l >> 4) * 4 + rg;
                cand[(size_t)row * 32 + g * 4 + w] =
                    make_float4(a1, __int_as_float(b1), a2, __int_as_float(b2));
            }
        }
}

// ---------------- rescore: exact top-4 of 32 subset-pairs, fp64 re-eval ------
__global__ __launch_bounds__(256) void rescore_kernel(const float4* __restrict__ cand,
                                                      const float* __restrict__ X,
                                                      const float* __restrict__ CB,
                                                      int* __restrict__ idx,
                                                      float* __restrict__ encOut) {
    int w = threadIdx.x >> 6, l = threadIdx.x & 63;
    int r = blockIdx.x * 4 + w;
    float a0, a1, a2, a3; int j0, j1, j2, j3;
    if (l < 32) {
        float4 c = cand[(size_t)r * 32 + l];
        a0 = c.x; j0 = __float_as_int(c.y);
        a1 = c.z; j1 = __float_as_int(c.w);
    } else { a0 = INFINITY; a1 = INFINITY; j0 = 0x7fffffff; j1 = 0x7fffffff; }
    a2 = INFINITY; a3 = INFINITY; j2 = 0x7fffffff; j3 = 0x7fffffff;
    #pragma unroll
    for (int off = 32; off >= 1; off >>= 1) {
        float b0 = __shfl_xor(a0, off, 64), b1 = __shfl_xor(a1, off, 64);
        float b2 = __shfl_xor(a2, off, 64), b3 = __shfl_xor(a3, off, 64);
        int p0 = __shfl_xor(j0, off, 64), p1 = __shfl_xor(j1, off, 64);
        int p2 = __shfl_xor(j2, off, 64), p3 = __shfl_xor(j3, off, 64);
        pickmin(a0, j0, b3, p3); pickmin(a1, j1, b2, p2);
        pickmin(a2, j2, b1, p1); pickmin(a3, j3, b0, p0);
        ce4(a0, j0, a2, j2); ce4(a1, j1, a3, j3);
        ce4(a0, j0, a1, j1); ce4(a2, j2, a3, j3);
    }
    double dot0 = 0, dot1 = 0, dot2 = 0, dot3 = 0;
    double nn0 = 0, nn1 = 0, nn2 = 0, nn3 = 0;
    const float* xr = X + (size_t)r * C_;
    #pragma unroll
    for (int jj = 0; jj < 12; ++jj) {
        int c = l * 12 + jj;
        double x = (double)xr[c];
        double c0 = (double)CB[(size_t)j0 * C_ + c]; dot0 += x * c0; nn0 += c0 * c0;
        double c1 = (double)CB[(size_t)j1 * C_ + c]; dot1 += x * c1; nn1 += c1 * c1;
        double c2 = (double)CB[(size_t)j2 * C_ + c]; dot2 += x * c2; nn2 += c2 * c2;
        double c3 = (double)CB[(size_t)j3 * C_ + c]; dot3 += x * c3; nn3 += c3 * c3;
    }
    #pragma unroll
    for (int off = 32; off >= 1; off >>= 1) {
        dot0 += __shfl_xor(dot0, off, 64); dot1 += __shfl_xor(dot1, off, 64);
        dot2 += __shfl_xor(dot2, off, 64); dot3 += __shfl_xor(dot3, off, 64);
        nn0 += __shfl_xor(nn0, off, 64); nn1 += __shfl_xor(nn1, off, 64);
        nn2 += __shfl_xor(nn2, off, 64); nn3 += __shfl_xor(nn3, off, 64);
    }
    if (l == 0) {
        double d0 = nn0 - 2.0 * dot0, d1 = nn1 - 2.0 * dot1;
        double d2 = nn2 - 2.0 * dot2, d3 = nn3 - 2.0 * dot3;
        double best = d0; int bi = j0;
        if (d1 < best || (d1 == best && j1 < bi)) { best = d1; bi = j1; }
        if (d2 < best || (d2 == best && j2 < bi)) { best = d2; bi = j2; }
        if (d3 < best || (d3 == best && j3 < bi)) { best = d3; bi = j3; }
        idx[r] = bi;
        encOut[r] = (float)bi;
    }
}

// ---------------- motion conv GEMM (int8): XW[12544][16] ----------------
__global__ __launch_bounds__(256) void convgemm_i8_kernel(const char* __restrict__ Aq,
                                                          const char* __restrict__ Bq,
                                                          float* __restrict__ out) {
    __shared__ __align__(16) char AqL[8 * 1024];
    __shared__ __align__(16) char BqL[1024];
    const int tid = threadIdx.x;
    const int l = tid & 63, w = tid >> 6;
    const int rg0 = blockIdx.x * 8, row0 = blockIdx.x * 128;
    i32x4 acc[2];
    acc[0] = (i32x4){0, 0, 0, 0}; acc[1] = (i32x4){0, 0, 0, 0};
    #pragma unroll 1
    for (int st = 0; st < 12; ++st) {
        __syncthreads();
        #pragma unroll
        for (int i = 0; i < 3; ++i) {
            int s = w * 3 + i;
            if (s < 8)
                gload_lds16(&Aq[(((size_t)(rg0 + s) * 12 + st) << 10) + l * 16], &AqL[s << 10]);
            else if (s == 8)
                gload_lds16(&Bq[((size_t)st << 10) + l * 16], &BqL[0]);
        }
        __syncthreads();
        i32x4 bq = *(const i32x4*)&BqL[l * 16];
        #pragma unroll
        for (int mf = 0; mf < 2; ++mf) {
            i32x4 aq = *(const i32x4*)&AqL[((w * 2 + mf) << 10) + l * 16];
            acc[mf] = __builtin_amdgcn_mfma_i32_16x16x64_i8(aq, bq, acc[mf], 0, 0, 0);
        }
    }
    #pragma unroll
    for (int mf = 0; mf < 2; ++mf)
        #pragma unroll
        for (int rg = 0; rg < 4; ++rg) {
            int row = row0 + w * 32 + mf * 16 + (l >> 4) * 4 + rg;
            out[(size_t)row * 16 + (l & 15)] = (float)acc[mf][rg] * (1.f / 32768.f);
        }
}

// ---------------- bf16 conv GEMM (region mask): out[12544][NF*16] -----------
template<int NF>
__global__ __launch_bounds__(256) void convgemm_kernel(const ushort_t* __restrict__ Ahi_g,
                                                       const ushort_t* __restrict__ Bhi_g,
                                                       float* __restrict__ out) {
    __shared__ __align__(16) ushort_t AhL[16 * 512];
    __shared__ __align__(16) ushort_t BhL[NF * 2 * 512];
    const int TOT = 16 + 2 * NF;
    const int PW = (TOT + 3) >> 2;
    const int tid = threadIdx.x;
    const int l = tid & 63, w = tid >> 6;
    const int rg0 = blockIdx.x * 8;
    const int row0 = blockIdx.x * 128;
    f32x4 acc[2][NF];
    #pragma unroll
    for (int mf = 0; mf < 2; ++mf)
        #pragma unroll
        for (int nf = 0; nf < NF; ++nf) acc[mf][nf] = (f32x4){0.f, 0.f, 0.f, 0.f};
    #pragma unroll 1
    for (int st = 0; st < 12; ++st) {
        __syncthreads();
        #pragma unroll
        for (int i = 0; i < PW; ++i) {
            int s = w * PW + i;
            if (s < 16) {
                int rb = s >> 1, kb = s & 1;
                gload_lds16(&Ahi_g[(((size_t)(rg0 + rb) * 24 + st * 2 + kb) << 9) + l * 8], &AhL[s << 9]);
            } else if (s < TOT) {
                int t2 = s - 16;
                int cb = t2 >> 1, kb = t2 & 1;
                gload_lds16(&Bhi_g[(((size_t)cb * 24 + st * 2 + kb) << 9) + l * 8], &BhL[t2 << 9]);
            }
        }
        __syncthreads();
        #pragma unroll
        for (int kf = 0; kf < 2; ++kf) {
            short8v ah[2];
            #pragma unroll
            for (int mf = 0; mf < 2; ++mf)
                ah[mf] = *(const short8v*)&AhL[(((w * 2 + mf) * 2 + kf) << 9) + l * 8];
            #pragma unroll
            for (int nf = 0; nf < NF; ++nf) {
                short8v bh = *(const short8v*)&BhL[((nf * 2 + kf) << 9) + l * 8];
                #pragma unroll
                for (int mf = 0; mf < 2; ++mf)
                    acc[mf][nf] = __builtin_amdgcn_mfma_f32_16x16x32_bf16(ah[mf], bh, acc[mf][nf], 0, 0, 0);
            }
        }
    }
    #pragma unroll
    for (int mf = 0; mf < 2; ++mf)
        #pragma unroll
        for (int nf = 0; nf < NF; ++nf)
            #pragma unroll
            for (int rg = 0; rg < 4; ++rg) {
                int row = row0 + w * 32 + mf * 16 + (l >> 4) * 4 + rg;
                out[(size_t)row * (NF * 16) + nf * 16 + (l & 15)] = acc[mf][nf][rg];
            }
}

// ---------------- generic frag-GEMM with bias: out[M][N] fp32 ----------------
template<int NF>
__global__ __launch_bounds__(256) void gemm_frag_kernel(const ushort_t* __restrict__ Af,
                                                        const ushort_t* __restrict__ Bf,
                                                        const float* __restrict__ bias,
                                                        float* __restrict__ out, int N) {
    __shared__ __align__(16) ushort_t AhL[16 * 512];
    __shared__ __align__(16) ushort_t BhL[2 * NF * 512];
    const int TOT = 16 + 2 * NF;
    const int PW = (TOT + 3) >> 2;
    const int tid = threadIdx.x;
    const int l = tid & 63, w = tid >> 6;
    const int rg0 = blockIdx.x * 8, row0 = blockIdx.x * 128;
    const int cb0 = blockIdx.y * NF;
    f32x4 acc[2][NF];
    #pragma unroll
    for (int mf = 0; mf < 2; ++mf)
        #pragma unroll
        for (int nf = 0; nf < NF; ++nf) acc[mf][nf] = (f32x4){0.f, 0.f, 0.f, 0.f};
    #pragma unroll 1
    for (int st = 0; st < 12; ++st) {
        __syncthreads();
        #pragma unroll
        for (int i = 0; i < PW; ++i) {
            int s = w * PW + i;
            if (s < 16) {
                int rb = s >> 1, kb = s & 1;
                gload_lds16(&Af[(((size_t)(rg0 + rb) * 24 + st * 2 + kb) << 9) + l * 8], &AhL[s << 9]);
            } else if (s < TOT) {
                int t2 = s - 16;
                int cb = t2 >> 1, kb = t2 & 1;
                gload_lds16(&Bf[(((size_t)(cb0 + cb) * 24 + st * 2 + kb) << 9) + l * 8], &BhL[t2 << 9]);
            }
        }
        __syncthreads();
        #pragma unroll
        for (int kf = 0; kf < 2; ++kf) {
            short8v ah[2];
            #pragma unroll
            for (int mf = 0; mf < 2; ++mf)
                ah[mf] = *(const short8v*)&AhL[(((w * 2 + mf) * 2 + kf) << 9) + l * 8];
            #pragma unroll
            for (int nf = 0; nf < NF; ++nf) {
                short8v bh = *(const short8v*)&BhL[((nf * 2 + kf) << 9) + l * 8];
                #pragma unroll
                for (int mf = 0; mf < 2; ++mf)
                    acc[mf][nf] = __builtin_amdgcn_mfma_f32_16x16x32_bf16(ah[mf], bh, acc[mf][nf], 0, 0, 0);
            }
        }
    }
    #pragma unroll
    for (int mf = 0; mf < 2; ++mf)
        #pragma unroll
        for (int nf = 0; nf < NF; ++nf) {
            int col = (cb0 + nf) * 16 + (l & 15);
            float bv = bias[col];
            #pragma unroll
            for (int rg = 0; rg < 4; ++rg) {
                int row = row0 + w * 32 + mf * 16 + (l >> 4) * 4 + rg;
                out[(size_t)row * N + col] = acc[mf][nf][rg] + bv;
            }
        }
}

// ---------------- mm finish: shifted-add + frame diff + softmax --------------
__global__ __launch_bounds__(256) void mm_finish_kernel(const float* __restrict__ XW,
                                                        const float* __restrict__ ex_b,
                                                        float* __restrict__ sm) {
    int b = blockIdx.x, t = threadIdx.x;
    float val = -INFINITY;
    if (t < L_) {
        if ((b & 3) == 0) val = ex_b[0];
        else {
            int yy = t / HW_, xx = t - (t / HW_) * HW_;
            float acc = 0.f;
            #pragma unroll
            for (int dy = 0; dy < 3; ++dy) {
                int sy = yy + dy - 1; if (sy < 0 || sy >= HW_) continue;
                #pragma unroll
                for (int dx = 0; dx < 3; ++dx) {
                    int sx = xx + dx - 1; if (sx < 0 || sx >= HW_) continue;
                    int q = sy * HW_ + sx, tap = dy * 3 + dx;
                    acc += XW[((size_t)b * L_ + q) * 16 + tap]
                         - XW[((size_t)(b - 1) * L_ + q) * 16 + tap];
                }
            }
            val = acc + ex_b[0];
        }
    }
    __shared__ float red[4];
    float mw = wave_reduce_max(val);
    if ((t & 63) == 0) red[t >> 6] = mw;
    __syncthreads();
    float mx = fmaxf(fmaxf(red[0], red[1]), fmaxf(red[2], red[3]));
    float e = (t < L_) ? expf(val - mx) : 0.f;
    __syncthreads();
    float sw = wave_reduce_sum(e);
    if ((t & 63) == 0) red[t >> 6] = sw;
    __syncthreads();
    float s = red[0] + red[1] + red[2] + red[3];
    if (t < L_) sm[b * L_ + t] = e / s;
}

// ---------------- vqf -> fragment-linear bf16 ----------------
__global__ __launch_bounds__(256) void vqf_split_kernel(const float* __restrict__ X,
                                                        const float* __restrict__ CB,
                                                        const int* __restrict__ idx,
                                                        const float* __restrict__ sm,
                                                        ushort_t* __restrict__ Vhi) {
    const int rg = blockIdx.x, t = threadIdx.x;
    #pragma unroll
    for (int i = 0; i < 6; ++i) {
        int s = t + i * 256;
        int kb = s >> 6, l = s & 63;
        int row = rg * 16 + (l & 15);
        int k = kb * 32 + ((l >> 4) << 3);
        int kidx = idx[row];
        float sc = sm[row];
        const float* xp = &X[(size_t)row * C_ + k];
        const float* cp = &CB[(size_t)kidx * C_ + k];
        union { ushort_t u[8]; short8v v; } H;
        #pragma unroll
        for (int e = 0; e < 8; ++e) H.u[e] = f2bf_rne(cp[e] + xp[e] * sc);
        *(short8v*)&Vhi[((size_t)rg * 1536 + s) * 8] = H.v;
    }
}

// ---------------- rm finish: shifted-add of OUTC + bias ----------------
__global__ __launch_bounds__(256) void rm_finish_kernel(const float* __restrict__ OUTC,
                                                        const float* __restrict__ att_b,
                                                        float* __restrict__ rmOut) {
    int gid = blockIdx.x * 256 + threadIdx.x;
    if (gid >= B_ * R_ * L_) return;
    int b = gid / (R_ * L_);
    int rem = gid - b * (R_ * L_);
    int r = rem / L_, p = rem - r * L_;
    int yy = p / HW_, xx = p - yy * HW_;
    float acc = att_b[r];
    #pragma unroll
    for (int dy = 0; dy < 3; ++dy) {
        int sy = yy + dy - 1; if (sy < 0 || sy >= HW_) continue;
        #pragma unroll
        for (int dx = 0; dx < 3; ++dx) {
            int sx = xx + dx - 1; if (sx < 0 || sx >= HW_) continue;
            int q = sy * HW_ + sx, tap = dy * 3 + dx;
            acc += OUTC[((size_t)b * L_ + q) * 80 + tap * 8 + r];
        }
    }
    rmOut[gid] = acc;
}

// ---------------- regions einsum from Vhi -> seq frags (bf16) ----------------
__global__ __launch_bounds__(256) void regions_kernel(const ushort_t* __restrict__ Vhi,
                                                      const float* __restrict__ rm,
                                                      ushort_t* __restrict__ seqF) {
    int b = blockIdx.x, cg = blockIdx.y, t = threadIdx.x;
    __shared__ float rms[R_ * L_];
    for (int i = t; i < R_ * L_; i += 256) rms[i] = rm[(size_t)b * R_ * L_ + i];
    __syncthreads();
    const float inv = 1.f / 196.f;
    int c = cg * 256 + t;
    int kb = c >> 5, q = (c >> 3) & 3, e = c & 7;
    float acc[R_] = {};
    for (int p = 0; p < L_; ++p) {
        int row = b * L_ + p;
        int rg = row >> 4, rr = row & 15;
        size_t a = (((size_t)rg * 24 + kb) * 64 + q * 16 + rr) * 8 + e;
        float x = bf2f(Vhi[a]);
        #pragma unroll
        for (int r = 0; r < R_; ++r) acc[r] += x * rms[r * L_ + p];
    }
    #pragma unroll
    for (int r = 0; r < R_; ++r) {
        int row = b * 8 + r;
        int rg2 = row >> 4, rr = row & 15;
        seqF[(((size_t)rg2 * 24 + kb) * 64 + q * 16 + rr) * 8 + e] = f2bf_rne(acc[r] * inv);
    }
}

// ---------------- per-(batch,head) attention -> frag-linear bf16 out ---------
__global__ __launch_bounds__(256) void attn_kernel(const float* __restrict__ qkv,
                                                   ushort_t* __restrict__ outF) {
    int bp = blockIdx.x, h = blockIdx.y;
    __shared__ float qs[NT_][DH_], ks[NT_][DH_], vs[NT_][DH_];
    __shared__ float sc[NT_][NT_ + 1];
    int tid = threadIdx.x;
    for (int e = tid; e < NT_ * DH_; e += 256) {
        int n = e / DH_, d = e - n * DH_;
        size_t base = ((size_t)(bp * NT_ + n)) * 2304 + h * DH_ + d;
        qs[n][d] = qkv[base];
        ks[n][d] = qkv[base + 768];
        vs[n][d] = qkv[base + 1536];
    }
    __syncthreads();
    const float scale = 1.0f / sqrtf((float)DH_);
    for (int e = tid; e < NT_ * NT_; e += 256) {
        int n = e >> 5, m = e & 31;
        float s = 0.f;
        #pragma unroll 8
        for (int d = 0; d < DH_; ++d) s += qs[n][d] * ks[m][d];
        sc[n][m] = s * scale;
    }
    __syncthreads();
    if (tid < NT_) {
        float mx = -INFINITY;
        #pragma unroll
        for (int m = 0; m < NT_; ++m) mx = fmaxf(mx, sc[tid][m]);
        float sum = 0.f;
        #pragma unroll
        for (int m = 0; m < NT_; ++m) { float e2 = expf(sc[tid][m] - mx); sc[tid][m] = e2; sum += e2; }
        float inv = 1.f / sum;
        #pragma unroll
        for (int m = 0; m < NT_; ++m) sc[tid][m] *= inv;
    }
    __syncthreads();
    for (int e = tid; e < NT_ * DH_; e += 256) {
        int n = e / DH_, d = e - n * DH_;
        float o = 0.f;
        #pragma unroll
        for (int m = 0; m < NT_; ++m) o += sc[n][m] * vs[m][d];
        int row = bp * NT_ + n, c = h * DH_ + d;
        outF[(((size_t)(row >> 4) * 24 + (c >> 5)) * 64 + ((c >> 3) & 3) * 16 + (row & 15)) * 8 + (c & 7)]
            = f2bf_rne(o);
    }
}

// ---------------- launch ----------------
extern "C" void kernel_launch(void* const* d_in, const int* in_sizes, int n_in,
                              void* d_out, int out_size, void* d_ws, size_t ws_size,
                              hipStream_t stream) {
    const float* in_feas  = (const float*)d_in[0];
    const float* codebook = (const float*)d_in[2];
    const float* att_w    = (const float*)d_in[3];
    const float* att_b    = (const float*)d_in[4];
    const float* ex_w     = (const float*)d_in[5];
    const float* ex_b     = (const float*)d_in[6];
    const float* qkv_w    = (const float*)d_in[7];
    const float* qkv_b    = (const float*)d_in[8];
    const float* proj_w   = (const float*)d_in[9];
    const float* proj_b   = (const float*)d_in[10];

    float* out    = (float*)d_out;
    float* outVd  = out;
    float* outEnc = out + 393216;
    float* outRm  = out + 393216 + 12544;

    float* ws = (float*)d_ws;
    // flat layout, no overlays (~57.7 MB)
    float*    cnq    = ws + 0;                          // 8,192
    float4*   cand   = (float4*)(ws + 8192);            // 1,605,632 fl
    char*     CBq    = (char*)(ws + 1613824);           // 1,572,864 fl
    char*     Aq     = (char*)(ws + 3186688);           // 2,408,448 fl
    ushort_t* attHi  = (ushort_t*)(ws + 5595136);       // 30,720 fl
    char*     exq    = (char*)(ws + 5625856);           // 3,072 fl
    ushort_t* wqkvF  = (ushort_t*)(ws + 5628928);       // 884,736 fl
    ushort_t* wprojF = (ushort_t*)(ws + 6513664);       // 294,912 fl
    int*      idx    = (int*)(ws + 6808576);            // 12,544
    float*    XW     = ws + 6821120;                    // 200,704
    float*    sm     = ws + 7021824;                    // 12,544
    ushort_t* Vhi    = (ushort_t*)(ws + 7034368);       // 4,816,896 fl
    float*    OUTC   = ws + 11851264;                   // 1,003,520
    ushort_t* seqF   = (ushort_t*)(ws + 12854784);      // 196,608 fl
    float*    qkvb   = ws + 13051392;                   // 1,179,648
    ushort_t* attnbF = (ushort_t*)(ws + 14231040);      // 196,608 fl -> 14,427,648

    hipLaunchKernelGGL(cbq_kernel, dim3(512), dim3(256), 0, stream, codebook, CBq, cnq);
    hipLaunchKernelGGL(aq_kernel, dim3(784), dim3(256), 0, stream, in_feas, Aq);
    hipLaunchKernelGGL(wsplit_kernel, dim3(33), dim3(256), 0, stream, att_w, ex_w, attHi, exq);
    hipLaunchKernelGGL(wgemm_split_kernel, dim3(1152), dim3(256), 0, stream,
                       qkv_w, proj_w, wqkvF, wprojF);
    hipLaunchKernelGGL(vq_i8_kernel, dim3(8, 196), dim3(256), 0, stream, Aq, CBq, cnq, cand);
    hipLaunchKernelGGL(convgemm_i8_kernel, dim3(98), dim3(256), 0, stream, Aq, exq, XW);
    hipLaunchKernelGGL(rescore_kernel, dim3(M_ / 4), dim3(256), 0, stream,
                       cand, in_feas, codebook, idx, outEnc);
    hipLaunchKernelGGL(mm_finish_kernel, dim3(B_), dim3(256), 0, stream, XW, ex_b, sm);
    hipLaunchKernelGGL(vqf_split_kernel, dim3(784), dim3(256), 0, stream,
                       in_feas, codebook, idx, sm, Vhi);
    hipLaunchKernelGGL((convgemm_kernel<5>), dim3(98), dim3(256), 0, stream, Vhi, attHi, OUTC);
    hipLaunchKernelGGL(rm_finish_kernel, dim3(392), dim3(256), 0, stream, OUTC, att_b, outRm);
    hipLaunchKernelGGL(regions_kernel, dim3(B_, 3), dim3(256), 0, stream, Vhi, outRm, seqF);
    hipLaunchKernelGGL((gemm_frag_kernel<8>), dim3(4, 18), dim3(256), 0, stream,
                       seqF, wqkvF, qkv_b, qkvb, 2304);
    hipLaunchKernelGGL(attn_kernel, dim3(BP_, NH_), dim3(256), 0, stream, qkvb, attnbF);
    hipLaunchKernelGGL((gemm_frag_kernel<8>), dim3(4, 6), dim3(256), 0, stream,
                       attnbF, wprojF, proj_b, outVd, 768);
}

// Round 11
// 344.884 us; speedup vs baseline: 1.0020x; 1.0001x over previous
//
#include <hip/hip_runtime.h>
#include <math.h>

#define B_   64
#define L_   196
#define C_   768
#define K_   8192
#define R_   8
#define HW_  14
#define M_   (B_*L_)     // 12544
#define NH_  8
#define DH_  96
#define BP_  16
#define NT_  32

typedef unsigned short ushort_t;
typedef __attribute__((ext_vector_type(8))) short short8v;   // 8 bf16 (4 VGPR)
typedef __attribute__((ext_vector_type(4))) float f32x4;     // MFMA 16x16 f32 acc
typedef __attribute__((ext_vector_type(4))) int   i32x4;     // MFMA i8 operands/acc

// ---------------- utilities ----------------
__device__ inline float wave_reduce_sum(float v) {
    #pragma unroll
    for (int o = 32; o >= 1; o >>= 1) v += __shfl_xor(v, o, 64);
    return v;
}
__device__ inline float wave_reduce_max(float v) {
    #pragma unroll
    for (int o = 32; o >= 1; o >>= 1) v = fmaxf(v, __shfl_xor(v, o, 64));
    return v;
}

__device__ inline ushort_t f2bf_rne(float f) {
    unsigned u = __float_as_uint(f);
    unsigned r = u + 0x7fffu + ((u >> 16) & 1u);
    return (ushort_t)(r >> 16);
}
__device__ inline float bf2f(ushort_t h) { return __uint_as_float(((unsigned)h) << 16); }

__device__ inline char q8(float f, float s) {
    int q = __float2int_rn(f * s);
    return (char)(q < -127 ? -127 : (q > 127 ? 127 : q));
}

__device__ inline void gload_lds16(const void* gsrc, void* ldst) {
    __builtin_amdgcn_global_load_lds(
        (const __attribute__((address_space(1))) unsigned int*)gsrc,
        (__attribute__((address_space(3))) unsigned int*)ldst, 16, 0, 0);
}

// merge two sorted pairs -> sorted top-2 of union (lowest-index tie-break)
__device__ inline void top2_merge(float& v1, int& i1, float& v2, int& i2,
                                  float w1, int j1, float w2, int j2) {
    bool fw = (v1 < w1) || (v1 == w1 && i1 <= j1);
    float a1 = fw ? v1 : w1;  int ai1 = fw ? i1 : j1;
    float lb = fw ? w1 : v1;  int lbi = fw ? j1 : i1;
    float wsv = fw ? v2 : w2; int wsi = fw ? i2 : j2;
    bool sb = (lb < wsv) || (lb == wsv && lbi < wsi);
    v1 = a1; i1 = ai1;
    v2 = sb ? lb : wsv; i2 = sb ? lbi : wsi;
}

__device__ inline void ce4(float& v0, int& j0, float& v1, int& j1) {
    bool sw = (v1 < v0) || (v1 == v0 && j1 < j0);
    float tv = sw ? v1 : v0, uv = sw ? v0 : v1;
    int tj = sw ? j1 : j0, uj = sw ? j0 : j1;
    v0 = tv; j0 = tj; v1 = uv; j1 = uj;
}
__device__ inline void pickmin(float& v, int& j, float bv, int bj) {
    if (bv < v || (bv == v && bj < j)) { v = bv; j = bj; }
}

// ---------------- codebook -> int8 frags + norms (fused) ----------------
// CBq layout: [cb_g(512)][kb(12)][l(64)][e(16)] bytes; code=cb_g*16+(l&15), k=kb*64+(l>>4)*16+e
__global__ __launch_bounds__(256) void cbq_kernel(const float* __restrict__ CB,
                                                  char* __restrict__ CBq,
                                                  float* __restrict__ cnq) {
    __shared__ float xs[16 * 776];
    const int t = threadIdx.x;
    const int blk = blockIdx.x;
    const float4* src = (const float4*)(CB + (size_t)blk * 16 * C_);
    #pragma unroll
    for (int i = 0; i < 12; ++i) {
        int idx4 = t + i * 256;
        int r = idx4 / 192, c4 = idx4 - r * 192;
        ((float4*)(xs + r * 776))[c4] = src[idx4];
    }
    __syncthreads();
    #pragma unroll
    for (int i = 0; i < 3; ++i) {
        int s = t + i * 256;
        int kb = s >> 6, l = s & 63;
        int row = l & 15;
        int k0 = kb * 64 + ((l >> 4) << 4);
        union { char c[16]; i32x4 v; } Q;
        #pragma unroll
        for (int e = 0; e < 16; ++e) Q.c[e] = q8(xs[row * 776 + k0 + e], 32.f);
        *(i32x4*)&CBq[(((size_t)blk * 12 + kb) << 10) + l * 16] = Q.v;
    }
    // norms: thread t -> row t&15, chunk t>>4 (48 elems)
    int row = t & 15, chunk = t >> 4;
    float sum = 0.f;
    #pragma unroll
    for (int j = 0; j < 48; ++j) { float v = xs[row * 776 + chunk * 48 + j]; sum += v * v; }
    sum += __shfl_xor(sum, 16, 64);
    sum += __shfl_xor(sum, 32, 64);
    __shared__ float red[4][16];
    if ((t & 63) < 16) red[t >> 6][t & 15] = sum;
    __syncthreads();
    if (t < 16) cnq[blk * 16 + t] = (red[0][t] + red[1][t] + red[2][t] + red[3][t]) * 1024.f;
}

// ---------------- A -> int8 frags ----------------
__global__ __launch_bounds__(256) void aq_kernel(const float* __restrict__ X,
                                                 char* __restrict__ Aq) {
    __shared__ float xs[16 * 776];
    const int t = threadIdx.x;
    const int rg = blockIdx.x;
    const float4* src = (const float4*)(X + (size_t)rg * 16 * C_);
    #pragma unroll
    for (int i = 0; i < 12; ++i) {
        int idx4 = t + i * 256;
        int r = idx4 / 192, c4 = idx4 - r * 192;
        ((float4*)(xs + r * 776))[c4] = src[idx4];
    }
    __syncthreads();
    #pragma unroll
    for (int i = 0; i < 3; ++i) {
        int s = t + i * 256;
        int kb = s >> 6, l = s & 63;
        int row = l & 15;
        int k0 = kb * 64 + ((l >> 4) << 4);
        union { char c[16]; i32x4 v; } Q;
        #pragma unroll
        for (int e = 0; e < 16; ++e) Q.c[e] = q8(xs[row * 776 + k0 + e], 32.f);
        *(i32x4*)&Aq[(((size_t)rg * 12 + kb) << 10) + l * 16] = Q.v;
    }
}

// ---------------- conv weights: att bf16 frags + ex int8 frags ----------------
__global__ __launch_bounds__(256) void wsplit_kernel(const float* __restrict__ att_w,
                                                     const float* __restrict__ ex_w,
                                                     ushort_t* __restrict__ attHi,
                                                     char* __restrict__ exq) {
    int gid = blockIdx.x * 256 + threadIdx.x;
    if (gid < 7680) {                                  // att bf16: 5 cb x 24 kb x 64 l
        int cb = gid / 1536;
        int rem = gid - cb * 1536;
        int l = rem & 63;
        int col = cb * 16 + (l & 15);
        int k = ((rem >> 6) << 5) + ((l >> 4) << 3);
        union { ushort_t u[8]; short8v v; } H;
        #pragma unroll
        for (int e = 0; e < 8; ++e) {
            int c = k + e;
            float f = (col < 72) ? att_w[(size_t)(col & 7) * 6912 + c * 9 + (col >> 3)] : 0.f;
            H.u[e] = f2bf_rne(f);
        }
        *(short8v*)&attHi[(size_t)gid * 8] = H.v;
    } else if (gid < 8448) {                           // ex int8: 12 kb x 64 l
        int g2 = gid - 7680;
        int l = g2 & 63;
        int col = l & 15;
        int k0 = ((g2 >> 6) << 6) + ((l >> 4) << 4);
        union { char c[16]; i32x4 v; } Q;
        #pragma unroll
        for (int e = 0; e < 16; ++e) {
            int k = k0 + e;
            float f = (col < 9) ? ex_w[k * 9 + col] : 0.f;
            Q.c[e] = q8(f, 1024.f);
        }
        *(i32x4*)&exq[(size_t)g2 * 16] = Q.v;
    }
}

// ---------------- qkv/proj weights -> bf16 frags ----------------
__global__ __launch_bounds__(256) void wgemm_split_kernel(const float* __restrict__ qkv_w,
                                                          const float* __restrict__ proj_w,
                                                          ushort_t* __restrict__ wqkvF,
                                                          ushort_t* __restrict__ wprojF) {
    int gid = blockIdx.x * 256 + threadIdx.x;
    const float* W; ushort_t* D; int g2;
    if (gid < 221184) { W = qkv_w; D = wqkvF; g2 = gid; }
    else { W = proj_w; D = wprojF; g2 = gid - 221184; }
    int cb = g2 / 1536;
    int rem = g2 - cb * 1536;
    int l = rem & 63;
    int col = cb * 16 + (l & 15);
    int k = ((rem >> 6) << 5) + ((l >> 4) << 3);
    union { ushort_t u[8]; short8v v; } H;
    #pragma unroll
    for (int e = 0; e < 8; ++e) H.u[e] = f2bf_rne(W[(size_t)col * 768 + k + e]);
    *(short8v*)&D[(size_t)g2 * 8] = H.v;
}

// ---------------- VQ: int8 MFMA, BM=64 BN=512 BK=64, dbuf + counted vmcnt ----
// grid (8, 196): g = code split (1024 codes, XCD-pinned), mt = 64-row tile
__global__ __launch_bounds__(256, 2) void vq_i8_kernel(const char* __restrict__ Aq,
                                                       const char* __restrict__ CBq,
                                                       const float* __restrict__ cnq,
                                                       float4* __restrict__ cand) {
    __shared__ __align__(16) char AqL[2][4096];
    __shared__ __align__(16) char BqL[2][32768];
    const int tid = threadIdx.x;
    const int l = tid & 63, w = tid >> 6;              // w = col quadrant 0..3
    const int g = blockIdx.x;
    const int mt = blockIdx.y;
    const int row0 = mt * 64;
    const int rg0 = mt * 4;

    float v1[4][4], v2[4][4]; int i1[4][4], i2[4][4];
    #pragma unroll
    for (int mf = 0; mf < 4; ++mf)
        #pragma unroll
        for (int rg = 0; rg < 4; ++rg) {
            v1[mf][rg] = INFINITY; v2[mf][rg] = INFINITY;
            i1[mf][rg] = 0x7fffffff; i2[mf][rg] = 0x7fffffff;
        }

    auto STAGE = [&](int buf, int u) {
        int ch = (u >= 12) ? 1 : 0;
        int st = u - ch * 12;
        int cbase = g * 64 + ch * 32;
        #pragma unroll
        for (int i = 0; i < 9; ++i) {
            int s = w * 9 + i;
            if (s < 4)
                gload_lds16(&Aq[(((size_t)(rg0 + s) * 12 + st) << 10) + l * 16],
                            &AqL[buf][s << 10]);
            else {
                int cb = s - 4;
                gload_lds16(&CBq[(((size_t)(cbase + cb) * 12 + st) << 10) + l * 16],
                            &BqL[buf][cb << 10]);
            }
        }
    };

    int cur = 0;
    STAGE(0, 0);
    __syncthreads();                                   // full drain once (prologue)

    #pragma unroll 1
    for (int ch = 0; ch < 2; ++ch) {
        i32x4 acc[4][8];
        #pragma unroll
        for (int mf = 0; mf < 4; ++mf)
            #pragma unroll
            for (int nf = 0; nf < 8; ++nf) acc[mf][nf] = (i32x4){0, 0, 0, 0};

        #pragma unroll 1
        for (int st = 0; st < 12; ++st) {
            int u = ch * 12 + st;
            if (u < 23) STAGE(cur ^ 1, u + 1);         // prefetch next stage
            i32x4 aq[4];
            #pragma unroll
            for (int mf = 0; mf < 4; ++mf)
                aq[mf] = *(const i32x4*)&AqL[cur][(mf << 10) + l * 16];
            #pragma unroll
            for (int nf = 0; nf < 8; ++nf) {
                i32x4 bq = *(const i32x4*)&BqL[cur][((w * 8 + nf) << 10) + l * 16];
                #pragma unroll
                for (int mf = 0; mf < 4; ++mf)
                    acc[mf][nf] = __builtin_amdgcn_mfma_i32_16x16x64_i8(aq[mf], bq, acc[mf][nf], 0, 0, 0);
            }
            // counted drain: wait only for the PREVIOUS buffer's loads (keep 9 in flight)
            asm volatile("s_waitcnt vmcnt(9)" ::: "memory");
            __builtin_amdgcn_sched_barrier(0);
            __builtin_amdgcn_s_barrier();
            __builtin_amdgcn_sched_barrier(0);
            cur ^= 1;
        }
        // chunk epilogue: d~ = 1024*(cn - 2 x.c); per-lane top-2 insert
        #pragma unroll
        for (int nf = 0; nf < 8; ++nf) {
            int code = g * 1024 + ch * 512 + w * 128 + nf * 16 + (l & 15);
            float cnv = cnq[code];
            #pragma unroll
            for (int mf = 0; mf < 4; ++mf)
                #pragma unroll
                for (int rg = 0; rg < 4; ++rg) {
                    float d = fmaf(-2.f, (float)acc[mf][nf][rg], cnv);
                    bool c1 = d < v1[mf][rg];
                    bool c2 = d < v2[mf][rg];
                    float nv2 = c1 ? v1[mf][rg] : (c2 ? d : v2[mf][rg]);
                    int   ni2 = c1 ? i1[mf][rg] : (c2 ? code : i2[mf][rg]);
                    v2[mf][rg] = nv2; i2[mf][rg] = ni2;
                    if (c1) { v1[mf][rg] = d; i1[mf][rg] = code; }
                }
        }
    }
    // cross-lane exact top-2 per row over the 16 col-lanes; write subset pair
    #pragma unroll
    for (int mf = 0; mf < 4; ++mf)
        #pragma unroll
        for (int rg = 0; rg < 4; ++rg) {
            float a1 = v1[mf][rg], a2 = v2[mf][rg];
            int b1 = i1[mf][rg], b2 = i2[mf][rg];
            #pragma unroll
            for (int off = 8; off >= 1; off >>= 1) {
                float w1 = __shfl_xor(a1, off, 64), w2 = __shfl_xor(a2, off, 64);
                int j1 = __shfl_xor(b1, off, 64), j2 = __shfl_xor(b2, off, 64);
                top2_merge(a1, b1, a2, b2, w1, j1, w2, j2);
            }
            if ((l & 15) == 0) {
                int row = row0 + mf * 16 + (l >> 4) * 4 + rg;
                cand[(size_t)row * 32 + g * 4 + w] =
                    make_float4(a1, __int_as_float(b1), a2, __int_as_float(b2));
            }
        }
}

// ---------------- rescore: exact top-4 of 32 subset-pairs, fp64 re-eval ------
__global__ __launch_bounds__(256) void rescore_kernel(const float4* __restrict__ cand,
                                                      const float* __restrict__ X,
                                                      const float* __restrict__ CB,
                                                      int* __restrict__ idx,
                                                      float* __restrict__ encOut) {
    int w = threadIdx.x >> 6, l = threadIdx.x & 63;
    int r = blockIdx.x * 4 + w;
    float a0, a1, a2, a3; int j0, j1, j2, j3;
    if (l < 32) {
        float4 c = cand[(size_t)r * 32 + l];
        a0 = c.x; j0 = __float_as_int(c.y);
        a1 = c.z; j1 = __float_as_int(c.w);
    } else { a0 = INFINITY; a1 = INFINITY; j0 = 0x7fffffff; j1 = 0x7fffffff; }
    a2 = INFINITY; a3 = INFINITY; j2 = 0x7fffffff; j3 = 0x7fffffff;
    #pragma unroll
    for (int off = 32; off >= 1; off >>= 1) {
        float b0 = __shfl_xor(a0, off, 64), b1 = __shfl_xor(a1, off, 64);
        float b2 = __shfl_xor(a2, off, 64), b3 = __shfl_xor(a3, off, 64);
        int p0 = __shfl_xor(j0, off, 64), p1 = __shfl_xor(j1, off, 64);
        int p2 = __shfl_xor(j2, off, 64), p3 = __shfl_xor(j3, off, 64);
        pickmin(a0, j0, b3, p3); pickmin(a1, j1, b2, p2);
        pickmin(a2, j2, b1, p1); pickmin(a3, j3, b0, p0);
        ce4(a0, j0, a2, j2); ce4(a1, j1, a3, j3);
        ce4(a0, j0, a1, j1); ce4(a2, j2, a3, j3);
    }
    double dot0 = 0, dot1 = 0, dot2 = 0, dot3 = 0;
    double nn0 = 0, nn1 = 0, nn2 = 0, nn3 = 0;
    const float* xr = X + (size_t)r * C_;
    #pragma unroll
    for (int jj = 0; jj < 12; ++jj) {
        int c = l * 12 + jj;
        double x = (double)xr[c];
        double c0 = (double)CB[(size_t)j0 * C_ + c]; dot0 += x * c0; nn0 += c0 * c0;
        double c1 = (double)CB[(size_t)j1 * C_ + c]; dot1 += x * c1; nn1 += c1 * c1;
        double c2 = (double)CB[(size_t)j2 * C_ + c]; dot2 += x * c2; nn2 += c2 * c2;
        double c3 = (double)CB[(size_t)j3 * C_ + c]; dot3 += x * c3; nn3 += c3 * c3;
    }
    #pragma unroll
    for (int off = 32; off >= 1; off >>= 1) {
        dot0 += __shfl_xor(dot0, off, 64); dot1 += __shfl_xor(dot1, off, 64);
        dot2 += __shfl_xor(dot2, off, 64); dot3 += __shfl_xor(dot3, off, 64);
        nn0 += __shfl_xor(nn0, off, 64); nn1 += __shfl_xor(nn1, off, 64);
        nn2 += __shfl_xor(nn2, off, 64); nn3 += __shfl_xor(nn3, off, 64);
    }
    if (l == 0) {
        double d0 = nn0 - 2.0 * dot0, d1 = nn1 - 2.0 * dot1;
        double d2 = nn2 - 2.0 * dot2, d3 = nn3 - 2.0 * dot3;
        double best = d0; int bi = j0;
        if (d1 < best || (d1 == best && j1 < bi)) { best = d1; bi = j1; }
        if (d2 < best || (d2 == best && j2 < bi)) { best = d2; bi = j2; }
        if (d3 < best || (d3 == best && j3 < bi)) { best = d3; bi = j3; }
        idx[r] = bi;
        encOut[r] = (float)bi;
    }
}

// ---------------- motion conv GEMM (int8): XW[12544][16] ----------------
__global__ __launch_bounds__(256) void convgemm_i8_kernel(const char* __restrict__ Aq,
                                                          const char* __restrict__ Bq,
                                                          float* __restrict__ out) {
    __shared__ __align__(16) char AqL[8 * 1024];
    __shared__ __align__(16) char BqL[1024];
    const int tid = threadIdx.x;
    const int l = tid & 63, w = tid >> 6;
    const int rg0 = blockIdx.x * 8, row0 = blockIdx.x * 128;
    i32x4 acc[2];
    acc[0] = (i32x4){0, 0, 0, 0}; acc[1] = (i32x4){0, 0, 0, 0};
    #pragma unroll 1
    for (int st = 0; st < 12; ++st) {
        __syncthreads();
        #pragma unroll
        for (int i = 0; i < 3; ++i) {
            int s = w * 3 + i;
            if (s < 8)
                gload_lds16(&Aq[(((size_t)(rg0 + s) * 12 + st) << 10) + l * 16], &AqL[s << 10]);
            else if (s == 8)
                gload_lds16(&Bq[((size_t)st << 10) + l * 16], &BqL[0]);
        }
        __syncthreads();
        i32x4 bq = *(const i32x4*)&BqL[l * 16];
        #pragma unroll
        for (int mf = 0; mf < 2; ++mf) {
            i32x4 aq = *(const i32x4*)&AqL[((w * 2 + mf) << 10) + l * 16];
            acc[mf] = __builtin_amdgcn_mfma_i32_16x16x64_i8(aq, bq, acc[mf], 0, 0, 0);
        }
    }
    #pragma unroll
    for (int mf = 0; mf < 2; ++mf)
        #pragma unroll
        for (int rg = 0; rg < 4; ++rg) {
            int row = row0 + w * 32 + mf * 16 + (l >> 4) * 4 + rg;
            out[(size_t)row * 16 + (l & 15)] = (float)acc[mf][rg] * (1.f / 32768.f);
        }
}

// ---------------- bf16 conv GEMM (region mask): out[12544][NF*16] -----------
template<int NF>
__global__ __launch_bounds__(256) void convgemm_kernel(const ushort_t* __restrict__ Ahi_g,
                                                       const ushort_t* __restrict__ Bhi_g,
                                                       float* __restrict__ out) {
    __shared__ __align__(16) ushort_t AhL[16 * 512];
    __shared__ __align__(16) ushort_t BhL[NF * 2 * 512];
    const int TOT = 16 + 2 * NF;
    const int PW = (TOT + 3) >> 2;
    const int tid = threadIdx.x;
    const int l = tid & 63, w = tid >> 6;
    const int rg0 = blockIdx.x * 8;
    const int row0 = blockIdx.x * 128;
    f32x4 acc[2][NF];
    #pragma unroll
    for (int mf = 0; mf < 2; ++mf)
        #pragma unroll
        for (int nf = 0; nf < NF; ++nf) acc[mf][nf] = (f32x4){0.f, 0.f, 0.f, 0.f};
    #pragma unroll 1
    for (int st = 0; st < 12; ++st) {
        __syncthreads();
        #pragma unroll
        for (int i = 0; i < PW; ++i) {
            int s = w * PW + i;
            if (s < 16) {
                int rb = s >> 1, kb = s & 1;
                gload_lds16(&Ahi_g[(((size_t)(rg0 + rb) * 24 + st * 2 + kb) << 9) + l * 8], &AhL[s << 9]);
            } else if (s < TOT) {
                int t2 = s - 16;
                int cb = t2 >> 1, kb = t2 & 1;
                gload_lds16(&Bhi_g[(((size_t)cb * 24 + st * 2 + kb) << 9) + l * 8], &BhL[t2 << 9]);
            }
        }
        __syncthreads();
        #pragma unroll
        for (int kf = 0; kf < 2; ++kf) {
            short8v ah[2];
            #pragma unroll
            for (int mf = 0; mf < 2; ++mf)
                ah[mf] = *(const short8v*)&AhL[(((w * 2 + mf) * 2 + kf) << 9) + l * 8];
            #pragma unroll
            for (int nf = 0; nf < NF; ++nf) {
                short8v bh = *(const short8v*)&BhL[((nf * 2 + kf) << 9) + l * 8];
                #pragma unroll
                for (int mf = 0; mf < 2; ++mf)
                    acc[mf][nf] = __builtin_amdgcn_mfma_f32_16x16x32_bf16(ah[mf], bh, acc[mf][nf], 0, 0, 0);
            }
        }
    }
    #pragma unroll
    for (int mf = 0; mf < 2; ++mf)
        #pragma unroll
        for (int nf = 0; nf < NF; ++nf)
            #pragma unroll
            for (int rg = 0; rg < 4; ++rg) {
                int row = row0 + w * 32 + mf * 16 + (l >> 4) * 4 + rg;
                out[(size_t)row * (NF * 16) + nf * 16 + (l & 15)] = acc[mf][nf][rg];
            }
}

// ---------------- generic frag-GEMM with bias: out[M][N] fp32 ----------------
template<int NF>
__global__ __launch_bounds__(256) void gemm_frag_kernel(const ushort_t* __restrict__ Af,
                                                        const ushort_t* __restrict__ Bf,
                                                        const float* __restrict__ bias,
                                                        float* __restrict__ out, int N) {
    __shared__ __align__(16) ushort_t AhL[16 * 512];
    __shared__ __align__(16) ushort_t BhL[2 * NF * 512];
    const int TOT = 16 + 2 * NF;
    const int PW = (TOT + 3) >> 2;
    const int tid = threadIdx.x;
    const int l = tid & 63, w = tid >> 6;
    const int rg0 = blockIdx.x * 8, row0 = blockIdx.x * 128;
    const int cb0 = blockIdx.y * NF;
    f32x4 acc[2][NF];
    #pragma unroll
    for (int mf = 0; mf < 2; ++mf)
        #pragma unroll
        for (int nf = 0; nf < NF; ++nf) acc[mf][nf] = (f32x4){0.f, 0.f, 0.f, 0.f};
    #pragma unroll 1
    for (int st = 0; st < 12; ++st) {
        __syncthreads();
        #pragma unroll
        for (int i = 0; i < PW; ++i) {
            int s = w * PW + i;
            if (s < 16) {
                int rb = s >> 1, kb = s & 1;
                gload_lds16(&Af[(((size_t)(rg0 + rb) * 24 + st * 2 + kb) << 9) + l * 8], &AhL[s << 9]);
            } else if (s < TOT) {
                int t2 = s - 16;
                int cb = t2 >> 1, kb = t2 & 1;
                gload_lds16(&Bf[(((size_t)(cb0 + cb) * 24 + st * 2 + kb) << 9) + l * 8], &BhL[t2 << 9]);
            }
        }
        __syncthreads();
        #pragma unroll
        for (int kf = 0; kf < 2; ++kf) {
            short8v ah[2];
            #pragma unroll
            for (int mf = 0; mf < 2; ++mf)
                ah[mf] = *(const short8v*)&AhL[(((w * 2 + mf) * 2 + kf) << 9) + l * 8];
            #pragma unroll
            for (int nf = 0; nf < NF; ++nf) {
                short8v bh = *(const short8v*)&BhL[((nf * 2 + kf) << 9) + l * 8];
                #pragma unroll
                for (int mf = 0; mf < 2; ++mf)
                    acc[mf][nf] = __builtin_amdgcn_mfma_f32_16x16x32_bf16(ah[mf], bh, acc[mf][nf], 0, 0, 0);
            }
        }
    }
    #pragma unroll
    for (int mf = 0; mf < 2; ++mf)
        #pragma unroll
        for (int nf = 0; nf < NF; ++nf) {
            int col = (cb0 + nf) * 16 + (l & 15);
            float bv = bias[col];
            #pragma unroll
            for (int rg = 0; rg < 4; ++rg) {
                int row = row0 + w * 32 + mf * 16 + (l >> 4) * 4 + rg;
                out[(size_t)row * N + col] = acc[mf][nf][rg] + bv;
            }
        }
}

// ---------------- mm finish: shifted-add + frame diff + softmax --------------
__global__ __launch_bounds__(256) void mm_finish_kernel(const float* __restrict__ XW,
                                                        const float* __restrict__ ex_b,
                                                        float* __restrict__ sm) {
    int b = blockIdx.x, t = threadIdx.x;
    float val = -INFINITY;
    if (t < L_) {
        if ((b & 3) == 0) val = ex_b[0];
        else {
            int yy = t / HW_, xx = t - (t / HW_) * HW_;
            float acc = 0.f;
            #pragma unroll
            for (int dy = 0; dy < 3; ++dy) {
                int sy = yy + dy - 1; if (sy < 0 || sy >= HW_) continue;
                #pragma unroll
                for (int dx = 0; dx < 3; ++dx) {
                    int sx = xx + dx - 1; if (sx < 0 || sx >= HW_) continue;
                    int q = sy * HW_ + sx, tap = dy * 3 + dx;
                    acc += XW[((size_t)b * L_ + q) * 16 + tap]
                         - XW[((size_t)(b - 1) * L_ + q) * 16 + tap];
                }
            }
            val = acc + ex_b[0];
        }
    }
    __shared__ float red[4];
    float mw = wave_reduce_max(val);
    if ((t & 63) == 0) red[t >> 6] = mw;
    __syncthreads();
    float mx = fmaxf(fmaxf(red[0], red[1]), fmaxf(red[2], red[3]));
    float e = (t < L_) ? expf(val - mx) : 0.f;
    __syncthreads();
    float sw = wave_reduce_sum(e);
    if ((t & 63) == 0) red[t >> 6] = sw;
    __syncthreads();
    float s = red[0] + red[1] + red[2] + red[3];
    if (t < L_) sm[b * L_ + t] = e / s;
}

// ---------------- vqf -> fragment-linear bf16 ----------------
__global__ __launch_bounds__(256) void vqf_split_kernel(const float* __restrict__ X,
                                                        const float* __restrict__ CB,
                                                        const int* __restrict__ idx,
                                                        const float* __restrict__ sm,
                                                        ushort_t* __restrict__ Vhi) {
    const int rg = blockIdx.x, t = threadIdx.x;
    #pragma unroll
    for (int i = 0; i < 6; ++i) {
        int s = t + i * 256;
        int kb = s >> 6, l = s & 63;
        int row = rg * 16 + (l & 15);
        int k = kb * 32 + ((l >> 4) << 3);
        int kidx = idx[row];
        float sc = sm[row];
        const float* xp = &X[(size_t)row * C_ + k];
        const float* cp = &CB[(size_t)kidx * C_ + k];
        union { ushort_t u[8]; short8v v; } H;
        #pragma unroll
        for (int e = 0; e < 8; ++e) H.u[e] = f2bf_rne(cp[e] + xp[e] * sc);
        *(short8v*)&Vhi[((size_t)rg * 1536 + s) * 8] = H.v;
    }
}

// ---------------- rm finish: shifted-add of OUTC + bias ----------------
__global__ __launch_bounds__(256) void rm_finish_kernel(const float* __restrict__ OUTC,
                                                        const float* __restrict__ att_b,
                                                        float* __restrict__ rmOut) {
    int gid = blockIdx.x * 256 + threadIdx.x;
    if (gid >= B_ * R_ * L_) return;
    int b = gid / (R_ * L_);
    int rem = gid - b * (R_ * L_);
    int r = rem / L_, p = rem - r * L_;
    int yy = p / HW_, xx = p - yy * HW_;
    float acc = att_b[r];
    #pragma unroll
    for (int dy = 0; dy < 3; ++dy) {
        int sy = yy + dy - 1; if (sy < 0 || sy >= HW_) continue;
        #pragma unroll
        for (int dx = 0; dx < 3; ++dx) {
            int sx = xx + dx - 1; if (sx < 0 || sx >= HW_) continue;
            int q = sy * HW_ + sx, tap = dy * 3 + dx;
            acc += OUTC[((size_t)b * L_ + q) * 80 + tap * 8 + r];
        }
    }
    rmOut[gid] = acc;
}

// ---------------- regions einsum from Vhi -> seq frags (bf16) ----------------
__global__ __launch_bounds__(256) void regions_kernel(const ushort_t* __restrict__ Vhi,
                                                      const float* __restrict__ rm,
                                                      ushort_t* __restrict__ seqF) {
    int b = blockIdx.x, cg = blockIdx.y, t = threadIdx.x;
    __shared__ float rms[R_ * L_];
    for (int i = t; i < R_ * L_; i += 256) rms[i] = rm[(size_t)b * R_ * L_ + i];
    __syncthreads();
    const float inv = 1.f / 196.f;
    int c = cg * 256 + t;
    int kb = c >> 5, q = (c >> 3) & 3, e = c & 7;
    float acc[R_] = {};
    for (int p = 0; p < L_; ++p) {
        int row = b * L_ + p;
        int rg = row >> 4, rr = row & 15;
        size_t a = (((size_t)rg * 24 + kb) * 64 + q * 16 + rr) * 8 + e;
        float x = bf2f(Vhi[a]);
        #pragma unroll
        for (int r = 0; r < R_; ++r) acc[r] += x * rms[r * L_ + p];
    }
    #pragma unroll
    for (int r = 0; r < R_; ++r) {
        int row = b * 8 + r;
        int rg2 = row >> 4, rr = row & 15;
        seqF[(((size_t)rg2 * 24 + kb) * 64 + q * 16 + rr) * 8 + e] = f2bf_rne(acc[r] * inv);
    }
}

// ---------------- per-(batch,head) attention -> frag-linear bf16 out ---------
__global__ __launch_bounds__(256) void attn_kernel(const float* __restrict__ qkv,
                                                   ushort_t* __restrict__ outF) {
    int bp = blockIdx.x, h = blockIdx.y;
    __shared__ float qs[NT_][DH_], ks[NT_][DH_], vs[NT_][DH_];
    __shared__ float sc[NT_][NT_ + 1];
    int tid = threadIdx.x;
    for (int e = tid; e < NT_ * DH_; e += 256) {
        int n = e / DH_, d = e - n * DH_;
        size_t base = ((size_t)(bp * NT_ + n)) * 2304 + h * DH_ + d;
        qs[n][d] = qkv[base];
        ks[n][d] = qkv[base + 768];
        vs[n][d] = qkv[base + 1536];
    }
    __syncthreads();
    const float scale = 1.0f / sqrtf((float)DH_);
    for (int e = tid; e < NT_ * NT_; e += 256) {
        int n = e >> 5, m = e & 31;
        float s = 0.f;
        #pragma unroll 8
        for (int d = 0; d < DH_; ++d) s += qs[n][d] * ks[m][d];
        sc[n][m] = s * scale;
    }
    __syncthreads();
    if (tid < NT_) {
        float mx = -INFINITY;
        #pragma unroll
        for (int m = 0; m < NT_; ++m) mx = fmaxf(mx, sc[tid][m]);
        float sum = 0.f;
        #pragma unroll
        for (int m = 0; m < NT_; ++m) { float e2 = expf(sc[tid][m] - mx); sc[tid][m] = e2; sum += e2; }
        float inv = 1.f / sum;
        #pragma unroll
        for (int m = 0; m < NT_; ++m) sc[tid][m] *= inv;
    }
    __syncthreads();
    for (int e = tid; e < NT_ * DH_; e += 256) {
        int n = e / DH_, d = e - n * DH_;
        float o = 0.f;
        #pragma unroll
        for (int m = 0; m < NT_; ++m) o += sc[n][m] * vs[m][d];
        int row = bp * NT_ + n, c = h * DH_ + d;
        outF[(((size_t)(row >> 4) * 24 + (c >> 5)) * 64 + ((c >> 3) & 3) * 16 + (row & 15)) * 8 + (c & 7)]
            = f2bf_rne(o);
    }
}

// ---------------- launch ----------------
extern "C" void kernel_launch(void* const* d_in, const int* in_sizes, int n_in,
                              void* d_out, int out_size, void* d_ws, size_t ws_size,
                              hipStream_t stream) {
    const float* in_feas  = (const float*)d_in[0];
    const float* codebook = (const float*)d_in[2];
    const float* att_w    = (const float*)d_in[3];
    const float* att_b    = (const float*)d_in[4];
    const float* ex_w     = (const float*)d_in[5];
    const float* ex_b     = (const float*)d_in[6];
    const float* qkv_w    = (const float*)d_in[7];
    const float* qkv_b    = (const float*)d_in[8];
    const float* proj_w   = (const float*)d_in[9];
    const float* proj_b   = (const float*)d_in[10];

    float* out    = (float*)d_out;
    float* outVd  = out;
    float* outEnc = out + 393216;
    float* outRm  = out + 393216 + 12544;

    float* ws = (float*)d_ws;
    // flat layout, no overlays (~57.7 MB)
    float*    cnq    = ws + 0;                          // 8,192
    float4*   cand   = (float4*)(ws + 8192);            // 1,605,632 fl
    char*     CBq    = (char*)(ws + 1613824);           // 1,572,864 fl
    char*     Aq     = (char*)(ws + 3186688);           // 2,408,448 fl
    ushort_t* attHi  = (ushort_t*)(ws + 5595136);       // 30,720 fl
    char*     exq    = (char*)(ws + 5625856);           // 3,072 fl
    ushort_t* wqkvF  = (ushort_t*)(ws + 5628928);       // 884,736 fl
    ushort_t* wprojF = (ushort_t*)(ws + 6513664);       // 294,912 fl
    int*      idx    = (int*)(ws + 6808576);            // 12,544
    float*    XW     = ws + 6821120;                    // 200,704
    float*    sm     = ws + 7021824;                    // 12,544
    ushort_t* Vhi    = (ushort_t*)(ws + 7034368);       // 4,816,896 fl
    float*    OUTC   = ws + 11851264;                   // 1,003,520
    ushort_t* seqF   = (ushort_t*)(ws + 12854784);      // 196,608 fl
    float*    qkvb   = ws + 13051392;                   // 1,179,648
    ushort_t* attnbF = (ushort_t*)(ws + 14231040);      // 196,608 fl -> 14,427,648

    hipLaunchKernelGGL(cbq_kernel, dim3(512), dim3(256), 0, stream, codebook, CBq, cnq);
    hipLaunchKernelGGL(aq_kernel, dim3(784), dim3(256), 0, stream, in_feas, Aq);
    hipLaunchKernelGGL(wsplit_kernel, dim3(33), dim3(256), 0, stream, att_w, ex_w, attHi, exq);
    hipLaunchKernelGGL(wgemm_split_kernel, dim3(1152), dim3(256), 0, stream,
                       qkv_w, proj_w, wqkvF, wprojF);
    hipLaunchKernelGGL(vq_i8_kernel, dim3(8, 196), dim3(256), 0, stream, Aq, CBq, cnq, cand);
    hipLaunchKernelGGL(convgemm_i8_kernel, dim3(98), dim3(256), 0, stream, Aq, exq, XW);
    hipLaunchKernelGGL(rescore_kernel, dim3(M_ / 4), dim3(256), 0, stream,
                       cand, in_feas, codebook, idx, outEnc);
    hipLaunchKernelGGL(mm_finish_kernel, dim3(B_), dim3(256), 0, stream, XW, ex_b, sm);
    hipLaunchKernelGGL(vqf_split_kernel, dim3(784), dim3(256), 0, stream,
                       in_feas, codebook, idx, sm, Vhi);
    hipLaunchKernelGGL((convgemm_kernel<5>), dim3(98), dim3(256), 0, stream, Vhi, attHi, OUTC);
    hipLaunchKernelGGL(rm_finish_kernel, dim3(392), dim3(256), 0, stream, OUTC, att_b, outRm);
    hipLaunchKernelGGL(regions_kernel, dim3(B_, 3), dim3(256), 0, stream, Vhi, outRm, seqF);
    hipLaunchKernelGGL((gemm_frag_kernel<8>), dim3(4, 18), dim3(256), 0, stream,
                       seqF, wqkvF, qkv_b, qkvb, 2304);
    hipLaunchKernelGGL(attn_kernel, dim3(BP_, NH_), dim3(256), 0, stream, qkvb, attnbF);
    hipLaunchKernelGGL((gemm_frag_kernel<8>), dim3(4, 6), dim3(256), 0, stream,
                       attnbF, wprojF, proj_b, outVd, 768);
}

// Round 12
// 312.639 us; speedup vs baseline: 1.1053x; 1.1031x over previous
//
#include <hip/hip_runtime.h>
#include <math.h>

#define B_   64
#define L_   196
#define C_   768
#define K_   8192
#define R_   8
#define HW_  14
#define M_   (B_*L_)     // 12544
#define NH_  8
#define DH_  96
#define BP_  16
#define NT_  32

typedef unsigned short ushort_t;
typedef __attribute__((ext_vector_type(8))) short short8v;   // 8 bf16 (4 VGPR)
typedef __attribute__((ext_vector_type(4))) float f32x4;     // MFMA 16x16 f32 acc
typedef __attribute__((ext_vector_type(4))) int   i32x4;     // MFMA i8 operands/acc

#define BIGF __uint_as_float(0x7F000000u)   // large finite sentinel (not INF: packing would NaN)

// ---------------- utilities ----------------
__device__ inline float wave_reduce_sum(float v) {
    #pragma unroll
    for (int o = 32; o >= 1; o >>= 1) v += __shfl_xor(v, o, 64);
    return v;
}
__device__ inline float wave_reduce_max(float v) {
    #pragma unroll
    for (int o = 32; o >= 1; o >>= 1) v = fmaxf(v, __shfl_xor(v, o, 64));
    return v;
}

__device__ inline ushort_t f2bf_rne(float f) {
    unsigned u = __float_as_uint(f);
    unsigned r = u + 0x7fffu + ((u >> 16) & 1u);
    return (ushort_t)(r >> 16);
}
__device__ inline float bf2f(ushort_t h) { return __uint_as_float(((unsigned)h) << 16); }

__device__ inline char q8(float f, float s) {
    int q = __float2int_rn(f * s);
    return (char)(q < -127 ? -127 : (q > 127 ? 127 : q));
}

__device__ inline void gload_lds16(const void* gsrc, void* ldst) {
    __builtin_amdgcn_global_load_lds(
        (const __attribute__((address_space(1))) unsigned int*)gsrc,
        (__attribute__((address_space(3))) unsigned int*)ldst, 16, 0, 0);
}

// ---------------- codebook -> int8 frags + norms (fused) ----------------
__global__ __launch_bounds__(256) void cbq_kernel(const float* __restrict__ CB,
                                                  char* __restrict__ CBq,
                                                  float* __restrict__ cnq) {
    __shared__ float xs[16 * 776];
    const int t = threadIdx.x;
    const int blk = blockIdx.x;
    const float4* src = (const float4*)(CB + (size_t)blk * 16 * C_);
    #pragma unroll
    for (int i = 0; i < 12; ++i) {
        int idx4 = t + i * 256;
        int r = idx4 / 192, c4 = idx4 - r * 192;
        ((float4*)(xs + r * 776))[c4] = src[idx4];
    }
    __syncthreads();
    #pragma unroll
    for (int i = 0; i < 3; ++i) {
        int s = t + i * 256;
        int kb = s >> 6, l = s & 63;
        int row = l & 15;
        int k0 = kb * 64 + ((l >> 4) << 4);
        union { char c[16]; i32x4 v; } Q;
        #pragma unroll
        for (int e = 0; e < 16; ++e) Q.c[e] = q8(xs[row * 776 + k0 + e], 32.f);
        *(i32x4*)&CBq[(((size_t)blk * 12 + kb) << 10) + l * 16] = Q.v;
    }
    int row = t & 15, chunk = t >> 4;
    float sum = 0.f;
    #pragma unroll
    for (int j = 0; j < 48; ++j) { float v = xs[row * 776 + chunk * 48 + j]; sum += v * v; }
    sum += __shfl_xor(sum, 16, 64);
    sum += __shfl_xor(sum, 32, 64);
    __shared__ float red[4][16];
    if ((t & 63) < 16) red[t >> 6][t & 15] = sum;
    __syncthreads();
    if (t < 16) cnq[blk * 16 + t] = (red[0][t] + red[1][t] + red[2][t] + red[3][t]) * 1024.f;
}

// ---------------- A -> int8 frags ----------------
__global__ __launch_bounds__(256) void aq_kernel(const float* __restrict__ X,
                                                 char* __restrict__ Aq) {
    __shared__ float xs[16 * 776];
    const int t = threadIdx.x;
    const int rg = blockIdx.x;
    const float4* src = (const float4*)(X + (size_t)rg * 16 * C_);
    #pragma unroll
    for (int i = 0; i < 12; ++i) {
        int idx4 = t + i * 256;
        int r = idx4 / 192, c4 = idx4 - r * 192;
        ((float4*)(xs + r * 776))[c4] = src[idx4];
    }
    __syncthreads();
    #pragma unroll
    for (int i = 0; i < 3; ++i) {
        int s = t + i * 256;
        int kb = s >> 6, l = s & 63;
        int row = l & 15;
        int k0 = kb * 64 + ((l >> 4) << 4);
        union { char c[16]; i32x4 v; } Q;
        #pragma unroll
        for (int e = 0; e < 16; ++e) Q.c[e] = q8(xs[row * 776 + k0 + e], 32.f);
        *(i32x4*)&Aq[(((size_t)rg * 12 + kb) << 10) + l * 16] = Q.v;
    }
}

// ---------------- conv weights: att bf16 frags + ex int8 frags ----------------
__global__ __launch_bounds__(256) void wsplit_kernel(const float* __restrict__ att_w,
                                                     const float* __restrict__ ex_w,
                                                     ushort_t* __restrict__ attHi,
                                                     char* __restrict__ exq) {
    int gid = blockIdx.x * 256 + threadIdx.x;
    if (gid < 7680) {
        int cb = gid / 1536;
        int rem = gid - cb * 1536;
        int l = rem & 63;
        int col = cb * 16 + (l & 15);
        int k = ((rem >> 6) << 5) + ((l >> 4) << 3);
        union { ushort_t u[8]; short8v v; } H;
        #pragma unroll
        for (int e = 0; e < 8; ++e) {
            int c = k + e;
            float f = (col < 72) ? att_w[(size_t)(col & 7) * 6912 + c * 9 + (col >> 3)] : 0.f;
            H.u[e] = f2bf_rne(f);
        }
        *(short8v*)&attHi[(size_t)gid * 8] = H.v;
    } else if (gid < 8448) {
        int g2 = gid - 7680;
        int l = g2 & 63;
        int col = l & 15;
        int k0 = ((g2 >> 6) << 6) + ((l >> 4) << 4);
        union { char c[16]; i32x4 v; } Q;
        #pragma unroll
        for (int e = 0; e < 16; ++e) {
            int k = k0 + e;
            float f = (col < 9) ? ex_w[k * 9 + col] : 0.f;
            Q.c[e] = q8(f, 1024.f);
        }
        *(i32x4*)&exq[(size_t)g2 * 16] = Q.v;
    }
}

// ---------------- qkv/proj weights -> bf16 frags ----------------
__global__ __launch_bounds__(256) void wgemm_split_kernel(const float* __restrict__ qkv_w,
                                                          const float* __restrict__ proj_w,
                                                          ushort_t* __restrict__ wqkvF,
                                                          ushort_t* __restrict__ wprojF) {
    int gid = blockIdx.x * 256 + threadIdx.x;
    const float* W; ushort_t* D; int g2;
    if (gid < 221184) { W = qkv_w; D = wqkvF; g2 = gid; }
    else { W = proj_w; D = wprojF; g2 = gid - 221184; }
    int cb = g2 / 1536;
    int rem = g2 - cb * 1536;
    int l = rem & 63;
    int col = cb * 16 + (l & 15);
    int k = ((rem >> 6) << 5) + ((l >> 4) << 3);
    union { ushort_t u[8]; short8v v; } H;
    #pragma unroll
    for (int e = 0; e < 8; ++e) H.u[e] = f2bf_rne(W[(size_t)col * 768 + k + e]);
    *(short8v*)&D[(size_t)g2 * 8] = H.v;
}

// ---------------- VQ: int8 MFMA, dbuf + counted vmcnt, packed-index top-2 ----
// grid (8, 196). Packed d: low 8 mantissa bits replaced by (ch<<7)|(nf<<4)|r.
// Perturbation <= 256 ulp(1.5e6) ~ 32 scaled units << quant noise (~700): selection
// only; fp64 rescore is exact on the candidates.
__global__ __launch_bounds__(256, 2) void vq_i8_kernel(const char* __restrict__ Aq,
                                                       const char* __restrict__ CBq,
                                                       const float* __restrict__ cnq,
                                                       float2* __restrict__ cand) {
    __shared__ __align__(16) char AqL[2][4096];
    __shared__ __align__(16) char BqL[2][32768];
    const int tid = threadIdx.x;
    const int l = tid & 63, w = tid >> 6;
    const int g = blockIdx.x;
    const int mt = blockIdx.y;
    const int row0 = mt * 64;
    const int rg0 = mt * 4;

    // per-thread constant byte-offsets for the 9 staged subtiles (strength-reduced)
    int K[9];
    #pragma unroll
    for (int i = 0; i < 9; ++i) {
        int s = w * 9 + i;
        K[i] = ((s < 4) ? (rg0 + s) * 12288 : (g * 64 + (s - 4)) * 12288) + l * 16;
    }
    // prefetch cn for all 16 codes this lane will score
    float cnr[2][8];
    #pragma unroll
    for (int ch = 0; ch < 2; ++ch)
        #pragma unroll
        for (int nf = 0; nf < 8; ++nf)
            cnr[ch][nf] = cnq[g * 1024 + ch * 512 + w * 128 + nf * 16 + (l & 15)];

    float v1[4][4], v2[4][4];
    #pragma unroll
    for (int mf = 0; mf < 4; ++mf)
        #pragma unroll
        for (int rg = 0; rg < 4; ++rg) { v1[mf][rg] = BIGF; v2[mf][rg] = BIGF; }

    auto STAGE = [&](int buf, int oA, int oB) {
        #pragma unroll
        for (int i = 0; i < 9; ++i) {
            int s = w * 9 + i;
            if (s < 4)
                gload_lds16((const char*)Aq + (unsigned)(K[i] + oA), &AqL[buf][s << 10]);
            else
                gload_lds16((const char*)CBq + (unsigned)(K[i] + oB), &BqL[buf][(s - 4) << 10]);
        }
    };

    int cur = 0;
    STAGE(0, 0, 0);
    __syncthreads();                                   // full drain once (prologue)
    int sA = 1024, sB = 1024;                          // uniform offsets for stage u+1

    #pragma unroll 1
    for (int ch = 0; ch < 2; ++ch) {
        i32x4 acc[4][8];
        #pragma unroll
        for (int mf = 0; mf < 4; ++mf)
            #pragma unroll
            for (int nf = 0; nf < 8; ++nf) acc[mf][nf] = (i32x4){0, 0, 0, 0};

        #pragma unroll 1
        for (int st = 0; st < 12; ++st) {
            int u = ch * 12 + st;
            if (u < 23) {
                STAGE(cur ^ 1, sA, sB);                // prefetch next stage
                bool wrap = (((u + 1) % 12) == 11);    // next-next crosses chunk
                sA += wrap ? -11264 : 1024;
                sB += wrap ? 381952 : 1024;
            }
            const char* aB = &AqL[cur][l * 16];
            const char* bB = &BqL[cur][(w * 8) * 1024 + l * 16];
            i32x4 aq[4];
            #pragma unroll
            for (int mf = 0; mf < 4; ++mf)
                aq[mf] = *(const i32x4*)(aB + (mf << 10));
            __builtin_amdgcn_s_setprio(1);
            #pragma unroll
            for (int nf = 0; nf < 8; ++nf) {
                i32x4 bq = *(const i32x4*)(bB + (nf << 10));
                #pragma unroll
                for (int mf = 0; mf < 4; ++mf)
                    acc[mf][nf] = __builtin_amdgcn_mfma_i32_16x16x64_i8(aq[mf], bq, acc[mf][nf], 0, 0, 0);
            }
            __builtin_amdgcn_s_setprio(0);
            // counted drain: wait only for the PREVIOUS buffer's loads (keep 9 in flight)
            asm volatile("s_waitcnt vmcnt(9)" ::: "memory");
            __builtin_amdgcn_sched_barrier(0);
            __builtin_amdgcn_s_barrier();
            __builtin_amdgcn_sched_barrier(0);
            cur ^= 1;
        }
        // chunk epilogue: packed-index top-2 insert (3 float ops/value)
        #pragma unroll
        for (int nf = 0; nf < 8; ++nf) {
            float cnv = cnr[ch][nf];
            unsigned tag = ((unsigned)ch << 7) | ((unsigned)nf << 4) | (unsigned)(l & 15);
            #pragma unroll
            for (int mf = 0; mf < 4; ++mf)
                #pragma unroll
                for (int rg = 0; rg < 4; ++rg) {
                    float d = fmaf(-2.f, (float)acc[mf][nf][rg], cnv);
                    float dp = __uint_as_float((__float_as_uint(d) & 0xFFFFFF00u) | tag);
                    float t = fmaxf(v1[mf][rg], dp);
                    v1[mf][rg] = fminf(v1[mf][rg], dp);
                    v2[mf][rg] = fminf(v2[mf][rg], t);
                }
        }
    }
    // cross-lane top-2 merge over the 16 col-lanes (pure float, index rides along)
    #pragma unroll
    for (int mf = 0; mf < 4; ++mf)
        #pragma unroll
        for (int rg = 0; rg < 4; ++rg) {
            float a1 = v1[mf][rg], a2 = v2[mf][rg];
            #pragma unroll
            for (int off = 8; off >= 1; off >>= 1) {
                float b1 = __shfl_xor(a1, off, 64), b2 = __shfl_xor(a2, off, 64);
                float m1 = fminf(a1, b1);
                float t  = fmaxf(a1, b1);
                a2 = fminf(t, fminf(a2, b2));
                a1 = m1;
            }
            if ((l & 15) == 0) {
                int row = row0 + mf * 16 + (l >> 4) * 4 + rg;
                cand[(size_t)row * 32 + g * 4 + w] = make_float2(a1, a2);
            }
        }
}

// ---------------- rescore: float-bitonic top-4 of 32 packed pairs, fp64 eval -
__global__ __launch_bounds__(256) void rescore_kernel(const float2* __restrict__ cand,
                                                      const float* __restrict__ X,
                                                      const float* __restrict__ CB,
                                                      int* __restrict__ idx,
                                                      float* __restrict__ encOut) {
    int w = threadIdx.x >> 6, l = threadIdx.x & 63;
    int r = blockIdx.x * 4 + w;
    float a0, a1, a2, a3;
    if (l < 32) {
        float2 c = cand[(size_t)r * 32 + l];
        unsigned b0 = __float_as_uint(c.x), b1 = __float_as_uint(c.y);
        // repack: [12:8]=subset lane, [7]=ch, [6:4]=nf, [3:0]=r
        a0 = __uint_as_float((b0 & 0xFFFFE000u) | ((unsigned)l << 8) | (b0 & 0xFFu));
        a1 = __uint_as_float((b1 & 0xFFFFE000u) | ((unsigned)l << 8) | (b1 & 0xFFu));
    } else { a0 = BIGF; a1 = BIGF; }
    a2 = BIGF; a3 = BIGF;
    #pragma unroll
    for (int off = 32; off >= 1; off >>= 1) {
        float b0 = __shfl_xor(a0, off, 64), b1 = __shfl_xor(a1, off, 64);
        float b2 = __shfl_xor(a2, off, 64), b3 = __shfl_xor(a3, off, 64);
        a0 = fminf(a0, b3); a1 = fminf(a1, b2);
        a2 = fminf(a2, b1); a3 = fminf(a3, b0);
        float lo, hi;
        lo = fminf(a0, a2); hi = fmaxf(a0, a2); a0 = lo; a2 = hi;
        lo = fminf(a1, a3); hi = fmaxf(a1, a3); a1 = lo; a3 = hi;
        lo = fminf(a0, a1); hi = fmaxf(a0, a1); a0 = lo; a1 = hi;
        lo = fminf(a2, a3); hi = fmaxf(a2, a3); a2 = lo; a3 = hi;
    }
    // decode the 4 candidate codes (all lanes agree)
    int jc[4];
    float av[4] = {a0, a1, a2, a3};
    #pragma unroll
    for (int k = 0; k < 4; ++k) {
        unsigned bits = __float_as_uint(av[k]);
        int s = (bits >> 8) & 31;
        jc[k] = (s >> 2) * 1024 + (int)((bits >> 7) & 1) * 512 + (s & 3) * 128
              + (int)((bits >> 4) & 7) * 16 + (int)(bits & 15);
    }
    int j0 = jc[0], j1 = jc[1], j2 = jc[2], j3 = jc[3];
    double dot0 = 0, dot1 = 0, dot2 = 0, dot3 = 0;
    double nn0 = 0, nn1 = 0, nn2 = 0, nn3 = 0;
    const float* xr = X + (size_t)r * C_;
    #pragma unroll
    for (int jj = 0; jj < 12; ++jj) {
        int c = l * 12 + jj;
        double x = (double)xr[c];
        double c0 = (double)CB[(size_t)j0 * C_ + c]; dot0 += x * c0; nn0 += c0 * c0;
        double c1 = (double)CB[(size_t)j1 * C_ + c]; dot1 += x * c1; nn1 += c1 * c1;
        double c2 = (double)CB[(size_t)j2 * C_ + c]; dot2 += x * c2; nn2 += c2 * c2;
        double c3 = (double)CB[(size_t)j3 * C_ + c]; dot3 += x * c3; nn3 += c3 * c3;
    }
    #pragma unroll
    for (int off = 32; off >= 1; off >>= 1) {
        dot0 += __shfl_xor(dot0, off, 64); dot1 += __shfl_xor(dot1, off, 64);
        dot2 += __shfl_xor(dot2, off, 64); dot3 += __shfl_xor(dot3, off, 64);
        nn0 += __shfl_xor(nn0, off, 64); nn1 += __shfl_xor(nn1, off, 64);
        nn2 += __shfl_xor(nn2, off, 64); nn3 += __shfl_xor(nn3, off, 64);
    }
    if (l == 0) {
        double d0 = nn0 - 2.0 * dot0, d1 = nn1 - 2.0 * dot1;
        double d2 = nn2 - 2.0 * dot2, d3 = nn3 - 2.0 * dot3;
        double best = d0; int bi = j0;
        if (d1 < best || (d1 == best && j1 < bi)) { best = d1; bi = j1; }
        if (d2 < best || (d2 == best && j2 < bi)) { best = d2; bi = j2; }
        if (d3 < best || (d3 == best && j3 < bi)) { best = d3; bi = j3; }
        idx[r] = bi;
        encOut[r] = (float)bi;
    }
}

// ---------------- motion conv GEMM (int8): XW[12544][16] ----------------
__global__ __launch_bounds__(256) void convgemm_i8_kernel(const char* __restrict__ Aq,
                                                          const char* __restrict__ Bq,
                                                          float* __restrict__ out) {
    __shared__ __align__(16) char AqL[8 * 1024];
    __shared__ __align__(16) char BqL[1024];
    const int tid = threadIdx.x;
    const int l = tid & 63, w = tid >> 6;
    const int rg0 = blockIdx.x * 8, row0 = blockIdx.x * 128;
    i32x4 acc[2];
    acc[0] = (i32x4){0, 0, 0, 0}; acc[1] = (i32x4){0, 0, 0, 0};
    #pragma unroll 1
    for (int st = 0; st < 12; ++st) {
        __syncthreads();
        #pragma unroll
        for (int i = 0; i < 3; ++i) {
            int s = w * 3 + i;
            if (s < 8)
                gload_lds16(&Aq[(((size_t)(rg0 + s) * 12 + st) << 10) + l * 16], &AqL[s << 10]);
            else if (s == 8)
                gload_lds16(&Bq[((size_t)st << 10) + l * 16], &BqL[0]);
        }
        __syncthreads();
        i32x4 bq = *(const i32x4*)&BqL[l * 16];
        #pragma unroll
        for (int mf = 0; mf < 2; ++mf) {
            i32x4 aq = *(const i32x4*)&AqL[((w * 2 + mf) << 10) + l * 16];
            acc[mf] = __builtin_amdgcn_mfma_i32_16x16x64_i8(aq, bq, acc[mf], 0, 0, 0);
        }
    }
    #pragma unroll
    for (int mf = 0; mf < 2; ++mf)
        #pragma unroll
        for (int rg = 0; rg < 4; ++rg) {
            int row = row0 + w * 32 + mf * 16 + (l >> 4) * 4 + rg;
            out[(size_t)row * 16 + (l & 15)] = (float)acc[mf][rg] * (1.f / 32768.f);
        }
}

// ---------------- bf16 conv GEMM (region mask): out[12544][NF*16] -----------
template<int NF>
__global__ __launch_bounds__(256) void convgemm_kernel(const ushort_t* __restrict__ Ahi_g,
                                                       const ushort_t* __restrict__ Bhi_g,
                                                       float* __restrict__ out) {
    __shared__ __align__(16) ushort_t AhL[16 * 512];
    __shared__ __align__(16) ushort_t BhL[NF * 2 * 512];
    const int TOT = 16 + 2 * NF;
    const int PW = (TOT + 3) >> 2;
    const int tid = threadIdx.x;
    const int l = tid & 63, w = tid >> 6;
    const int rg0 = blockIdx.x * 8;
    const int row0 = blockIdx.x * 128;
    f32x4 acc[2][NF];
    #pragma unroll
    for (int mf = 0; mf < 2; ++mf)
        #pragma unroll
        for (int nf = 0; nf < NF; ++nf) acc[mf][nf] = (f32x4){0.f, 0.f, 0.f, 0.f};
    #pragma unroll 1
    for (int st = 0; st < 12; ++st) {
        __syncthreads();
        #pragma unroll
        for (int i = 0; i < PW; ++i) {
            int s = w * PW + i;
            if (s < 16) {
                int rb = s >> 1, kb = s & 1;
                gload_lds16(&Ahi_g[(((size_t)(rg0 + rb) * 24 + st * 2 + kb) << 9) + l * 8], &AhL[s << 9]);
            } else if (s < TOT) {
                int t2 = s - 16;
                int cb = t2 >> 1, kb = t2 & 1;
                gload_lds16(&Bhi_g[(((size_t)cb * 24 + st * 2 + kb) << 9) + l * 8], &BhL[t2 << 9]);
            }
        }
        __syncthreads();
        #pragma unroll
        for (int kf = 0; kf < 2; ++kf) {
            short8v ah[2];
            #pragma unroll
            for (int mf = 0; mf < 2; ++mf)
                ah[mf] = *(const short8v*)&AhL[(((w * 2 + mf) * 2 + kf) << 9) + l * 8];
            #pragma unroll
            for (int nf = 0; nf < NF; ++nf) {
                short8v bh = *(const short8v*)&BhL[((nf * 2 + kf) << 9) + l * 8];
                #pragma unroll
                for (int mf = 0; mf < 2; ++mf)
                    acc[mf][nf] = __builtin_amdgcn_mfma_f32_16x16x32_bf16(ah[mf], bh, acc[mf][nf], 0, 0, 0);
            }
        }
    }
    #pragma unroll
    for (int mf = 0; mf < 2; ++mf)
        #pragma unroll
        for (int nf = 0; nf < NF; ++nf)
            #pragma unroll
            for (int rg = 0; rg < 4; ++rg) {
                int row = row0 + w * 32 + mf * 16 + (l >> 4) * 4 + rg;
                out[(size_t)row * (NF * 16) + nf * 16 + (l & 15)] = acc[mf][nf][rg];
            }
}

// ---------------- generic frag-GEMM with bias: out[M][N] fp32 ----------------
template<int NF>
__global__ __launch_bounds__(256) void gemm_frag_kernel(const ushort_t* __restrict__ Af,
                                                        const ushort_t* __restrict__ Bf,
                                                        const float* __restrict__ bias,
                                                        float* __restrict__ out, int N) {
    __shared__ __align__(16) ushort_t AhL[16 * 512];
    __shared__ __align__(16) ushort_t BhL[2 * NF * 512];
    const int TOT = 16 + 2 * NF;
    const int PW = (TOT + 3) >> 2;
    const int tid = threadIdx.x;
    const int l = tid & 63, w = tid >> 6;
    const int rg0 = blockIdx.x * 8, row0 = blockIdx.x * 128;
    const int cb0 = blockIdx.y * NF;
    f32x4 acc[2][NF];
    #pragma unroll
    for (int mf = 0; mf < 2; ++mf)
        #pragma unroll
        for (int nf = 0; nf < NF; ++nf) acc[mf][nf] = (f32x4){0.f, 0.f, 0.f, 0.f};
    #pragma unroll 1
    for (int st = 0; st < 12; ++st) {
        __syncthreads();
        #pragma unroll
        for (int i = 0; i < PW; ++i) {
            int s = w * PW + i;
            if (s < 16) {
                int rb = s >> 1, kb = s & 1;
                gload_lds16(&Af[(((size_t)(rg0 + rb) * 24 + st * 2 + kb) << 9) + l * 8], &AhL[s << 9]);
            } else if (s < TOT) {
                int t2 = s - 16;
                int cb = t2 >> 1, kb = t2 & 1;
                gload_lds16(&Bf[(((size_t)(cb0 + cb) * 24 + st * 2 + kb) << 9) + l * 8], &BhL[t2 << 9]);
            }
        }
        __syncthreads();
        #pragma unroll
        for (int kf = 0; kf < 2; ++kf) {
            short8v ah[2];
            #pragma unroll
            for (int mf = 0; mf < 2; ++mf)
                ah[mf] = *(const short8v*)&AhL[(((w * 2 + mf) * 2 + kf) << 9) + l * 8];
            #pragma unroll
            for (int nf = 0; nf < NF; ++nf) {
                short8v bh = *(const short8v*)&BhL[((nf * 2 + kf) << 9) + l * 8];
                #pragma unroll
                for (int mf = 0; mf < 2; ++mf)
                    acc[mf][nf] = __builtin_amdgcn_mfma_f32_16x16x32_bf16(ah[mf], bh, acc[mf][nf], 0, 0, 0);
            }
        }
    }
    #pragma unroll
    for (int mf = 0; mf < 2; ++mf)
        #pragma unroll
        for (int nf = 0; nf < NF; ++nf) {
            int col = (cb0 + nf) * 16 + (l & 15);
            float bv = bias[col];
            #pragma unroll
            for (int rg = 0; rg < 4; ++rg) {
                int row = row0 + w * 32 + mf * 16 + (l >> 4) * 4 + rg;
                out[(size_t)row * N + col] = acc[mf][nf][rg] + bv;
            }
        }
}

// ---------------- mm finish: shifted-add + frame diff + softmax --------------
__global__ __launch_bounds__(256) void mm_finish_kernel(const float* __restrict__ XW,
                                                        const float* __restrict__ ex_b,
                                                        float* __restrict__ sm) {
    int b = blockIdx.x, t = threadIdx.x;
    float val = -INFINITY;
    if (t < L_) {
        if ((b & 3) == 0) val = ex_b[0];
        else {
            int yy = t / HW_, xx = t - (t / HW_) * HW_;
            float acc = 0.f;
            #pragma unroll
            for (int dy = 0; dy < 3; ++dy) {
                int sy = yy + dy - 1; if (sy < 0 || sy >= HW_) continue;
                #pragma unroll
                for (int dx = 0; dx < 3; ++dx) {
                    int sx = xx + dx - 1; if (sx < 0 || sx >= HW_) continue;
                    int q = sy * HW_ + sx, tap = dy * 3 + dx;
                    acc += XW[((size_t)b * L_ + q) * 16 + tap]
                         - XW[((size_t)(b - 1) * L_ + q) * 16 + tap];
                }
            }
            val = acc + ex_b[0];
        }
    }
    __shared__ float red[4];
    float mw = wave_reduce_max(val);
    if ((t & 63) == 0) red[t >> 6] = mw;
    __syncthreads();
    float mx = fmaxf(fmaxf(red[0], red[1]), fmaxf(red[2], red[3]));
    float e = (t < L_) ? expf(val - mx) : 0.f;
    __syncthreads();
    float sw = wave_reduce_sum(e);
    if ((t & 63) == 0) red[t >> 6] = sw;
    __syncthreads();
    float s = red[0] + red[1] + red[2] + red[3];
    if (t < L_) sm[b * L_ + t] = e / s;
}

// ---------------- vqf -> fragment-linear bf16 ----------------
__global__ __launch_bounds__(256) void vqf_split_kernel(const float* __restrict__ X,
                                                        const float* __restrict__ CB,
                                                        const int* __restrict__ idx,
                                                        const float* __restrict__ sm,
                                                        ushort_t* __restrict__ Vhi) {
    const int rg = blockIdx.x, t = threadIdx.x;
    #pragma unroll
    for (int i = 0; i < 6; ++i) {
        int s = t + i * 256;
        int kb = s >> 6, l = s & 63;
        int row = rg * 16 + (l & 15);
        int k = kb * 32 + ((l >> 4) << 3);
        int kidx = idx[row];
        float sc = sm[row];
        const float* xp = &X[(size_t)row * C_ + k];
        const float* cp = &CB[(size_t)kidx * C_ + k];
        union { ushort_t u[8]; short8v v; } H;
        #pragma unroll
        for (int e = 0; e < 8; ++e) H.u[e] = f2bf_rne(cp[e] + xp[e] * sc);
        *(short8v*)&Vhi[((size_t)rg * 1536 + s) * 8] = H.v;
    }
}

// ---------------- rm finish: shifted-add of OUTC + bias ----------------
__global__ __launch_bounds__(256) void rm_finish_kernel(const float* __restrict__ OUTC,
                                                        const float* __restrict__ att_b,
                                                        float* __restrict__ rmOut) {
    int gid = blockIdx.x * 256 + threadIdx.x;
    if (gid >= B_ * R_ * L_) return;
    int b = gid / (R_ * L_);
    int rem = gid - b * (R_ * L_);
    int r = rem / L_, p = rem - r * L_;
    int yy = p / HW_, xx = p - yy * HW_;
    float acc = att_b[r];
    #pragma unroll
    for (int dy = 0; dy < 3; ++dy) {
        int sy = yy + dy - 1; if (sy < 0 || sy >= HW_) continue;
        #pragma unroll
        for (int dx = 0; dx < 3; ++dx) {
            int sx = xx + dx - 1; if (sx < 0 || sx >= HW_) continue;
            int q = sy * HW_ + sx, tap = dy * 3 + dx;
            acc += OUTC[((size_t)b * L_ + q) * 80 + tap * 8 + r];
        }
    }
    rmOut[gid] = acc;
}

// ---------------- regions einsum from Vhi -> seq frags (bf16) ----------------
__global__ __launch_bounds__(256) void regions_kernel(const ushort_t* __restrict__ Vhi,
                                                      const float* __restrict__ rm,
                                                      ushort_t* __restrict__ seqF) {
    int b = blockIdx.x, cg = blockIdx.y, t = threadIdx.x;
    __shared__ float rms[R_ * L_];
    for (int i = t; i < R_ * L_; i += 256) rms[i] = rm[(size_t)b * R_ * L_ + i];
    __syncthreads();
    const float inv = 1.f / 196.f;
    int c = cg * 256 + t;
    int kb = c >> 5, q = (c >> 3) & 3, e = c & 7;
    float acc[R_] = {};
    for (int p = 0; p < L_; ++p) {
        int row = b * L_ + p;
        int rg = row >> 4, rr = row & 15;
        size_t a = (((size_t)rg * 24 + kb) * 64 + q * 16 + rr) * 8 + e;
        float x = bf2f(Vhi[a]);
        #pragma unroll
        for (int r = 0; r < R_; ++r) acc[r] += x * rms[r * L_ + p];
    }
    #pragma unroll
    for (int r = 0; r < R_; ++r) {
        int row = b * 8 + r;
        int rg2 = row >> 4, rr = row & 15;
        seqF[(((size_t)rg2 * 24 + kb) * 64 + q * 16 + rr) * 8 + e] = f2bf_rne(acc[r] * inv);
    }
}

// ---------------- per-(batch,head) attention -> frag-linear bf16 out ---------
__global__ __launch_bounds__(256) void attn_kernel(const float* __restrict__ qkv,
                                                   ushort_t* __restrict__ outF) {
    int bp = blockIdx.x, h = blockIdx.y;
    __shared__ float qs[NT_][DH_], ks[NT_][DH_], vs[NT_][DH_];
    __shared__ float sc[NT_][NT_ + 1];
    int tid = threadIdx.x;
    for (int e = tid; e < NT_ * DH_; e += 256) {
        int n = e / DH_, d = e - n * DH_;
        size_t base = ((size_t)(bp * NT_ + n)) * 2304 + h * DH_ + d;
        qs[n][d] = qkv[base];
        ks[n][d] = qkv[base + 768];
        vs[n][d] = qkv[base + 1536];
    }
    __syncthreads();
    const float scale = 1.0f / sqrtf((float)DH_);
    for (int e = tid; e < NT_ * NT_; e += 256) {
        int n = e >> 5, m = e & 31;
        float s = 0.f;
        #pragma unroll 8
        for (int d = 0; d < DH_; ++d) s += qs[n][d] * ks[m][d];
        sc[n][m] = s * scale;
    }
    __syncthreads();
    if (tid < NT_) {
        float mx = -INFINITY;
        #pragma unroll
        for (int m = 0; m < NT_; ++m) mx = fmaxf(mx, sc[tid][m]);
        float sum = 0.f;
        #pragma unroll
        for (int m = 0; m < NT_; ++m) { float e2 = expf(sc[tid][m] - mx); sc[tid][m] = e2; sum += e2; }
        float inv = 1.f / sum;
        #pragma unroll
        for (int m = 0; m < NT_; ++m) sc[tid][m] *= inv;
    }
    __syncthreads();
    for (int e = tid; e < NT_ * DH_; e += 256) {
        int n = e / DH_, d = e - n * DH_;
        float o = 0.f;
        #pragma unroll
        for (int m = 0; m < NT_; ++m) o += sc[n][m] * vs[m][d];
        int row = bp * NT_ + n, c = h * DH_ + d;
        outF[(((size_t)(row >> 4) * 24 + (c >> 5)) * 64 + ((c >> 3) & 3) * 16 + (row & 15)) * 8 + (c & 7)]
            = f2bf_rne(o);
    }
}

// ---------------- launch ----------------
extern "C" void kernel_launch(void* const* d_in, const int* in_sizes, int n_in,
                              void* d_out, int out_size, void* d_ws, size_t ws_size,
                              hipStream_t stream) {
    const float* in_feas  = (const float*)d_in[0];
    const float* codebook = (const float*)d_in[2];
    const float* att_w    = (const float*)d_in[3];
    const float* att_b    = (const float*)d_in[4];
    const float* ex_w     = (const float*)d_in[5];
    const float* ex_b     = (const float*)d_in[6];
    const float* qkv_w    = (const float*)d_in[7];
    const float* qkv_b    = (const float*)d_in[8];
    const float* proj_w   = (const float*)d_in[9];
    const float* proj_b   = (const float*)d_in[10];

    float* out    = (float*)d_out;
    float* outVd  = out;
    float* outEnc = out + 393216;
    float* outRm  = out + 393216 + 12544;

    float* ws = (float*)d_ws;
    // same layout as R11 (cand region kept at float4 size; only half used now)
    float*    cnq    = ws + 0;                          // 8,192
    float2*   cand   = (float2*)(ws + 8192);            // uses 802,816 fl of 1,605,632 region
    char*     CBq    = (char*)(ws + 1613824);           // 1,572,864 fl
    char*     Aq     = (char*)(ws + 3186688);           // 2,408,448 fl
    ushort_t* attHi  = (ushort_t*)(ws + 5595136);       // 30,720 fl
    char*     exq    = (char*)(ws + 5625856);           // 3,072 fl
    ushort_t* wqkvF  = (ushort_t*)(ws + 5628928);       // 884,736 fl
    ushort_t* wprojF = (ushort_t*)(ws + 6513664);       // 294,912 fl
    int*      idx    = (int*)(ws + 6808576);            // 12,544
    float*    XW     = ws + 6821120;                    // 200,704
    float*    sm     = ws + 7021824;                    // 12,544
    ushort_t* Vhi    = (ushort_t*)(ws + 7034368);       // 4,816,896 fl
    float*    OUTC   = ws + 11851264;                   // 1,003,520
    ushort_t* seqF   = (ushort_t*)(ws + 12854784);      // 196,608 fl
    float*    qkvb   = ws + 13051392;                   // 1,179,648
    ushort_t* attnbF = (ushort_t*)(ws + 14231040);      // 196,608 fl -> 14,427,648

    hipLaunchKernelGGL(cbq_kernel, dim3(512), dim3(256), 0, stream, codebook, CBq, cnq);
    hipLaunchKernelGGL(aq_kernel, dim3(784), dim3(256), 0, stream, in_feas, Aq);
    hipLaunchKernelGGL(wsplit_kernel, dim3(33), dim3(256), 0, stream, att_w, ex_w, attHi, exq);
    hipLaunchKernelGGL(wgemm_split_kernel, dim3(1152), dim3(256), 0, stream,
                       qkv_w, proj_w, wqkvF, wprojF);
    hipLaunchKernelGGL(vq_i8_kernel, dim3(8, 196), dim3(256), 0, stream, Aq, CBq, cnq, cand);
    hipLaunchKernelGGL(convgemm_i8_kernel, dim3(98), dim3(256), 0, stream, Aq, exq, XW);
    hipLaunchKernelGGL(rescore_kernel, dim3(M_ / 4), dim3(256), 0, stream,
                       cand, in_feas, codebook, idx, outEnc);
    hipLaunchKernelGGL(mm_finish_kernel, dim3(B_), dim3(256), 0, stream, XW, ex_b, sm);
    hipLaunchKernelGGL(vqf_split_kernel, dim3(784), dim3(256), 0, stream,
                       in_feas, codebook, idx, sm, Vhi);
    hipLaunchKernelGGL((convgemm_kernel<5>), dim3(98), dim3(256), 0, stream, Vhi, attHi, OUTC);
    hipLaunchKernelGGL(rm_finish_kernel, dim3(392), dim3(256), 0, stream, OUTC, att_b, outRm);
    hipLaunchKernelGGL(regions_kernel, dim3(B_, 3), dim3(256), 0, stream, Vhi, outRm, seqF);
    hipLaunchKernelGGL((gemm_frag_kernel<8>), dim3(4, 18), dim3(256), 0, stream,
                       seqF, wqkvF, qkv_b, qkvb, 2304);
    hipLaunchKernelGGL(attn_kernel, dim3(BP_, NH_), dim3(256), 0, stream, qkvb, attnbF);
    hipLaunchKernelGGL((gemm_frag_kernel<8>), dim3(4, 6), dim3(256), 0, stream,
                       attnbF, wprojF, proj_b, outVd, 768);
}

// Round 13
// 298.873 us; speedup vs baseline: 1.1562x; 1.0461x over previous
//
#include <hip/hip_runtime.h>
#include <math.h>

#define B_   64
#define L_   196
#define C_   768
#define K_   8192
#define R_   8
#define HW_  14
#define M_   (B_*L_)     // 12544
#define NH_  8
#define DH_  96
#define BP_  16
#define NT_  32

typedef unsigned short ushort_t;
typedef __attribute__((ext_vector_type(8))) short short8v;   // 8 bf16 (4 VGPR)
typedef __attribute__((ext_vector_type(4))) float f32x4;     // MFMA 16x16 f32 acc
typedef __attribute__((ext_vector_type(4))) int   i32x4;     // MFMA i8 operands/acc

#define BIGF __uint_as_float(0x7F000000u)   // large finite sentinel

// ---------------- utilities ----------------
__device__ inline float wave_reduce_sum(float v) {
    #pragma unroll
    for (int o = 32; o >= 1; o >>= 1) v += __shfl_xor(v, o, 64);
    return v;
}
__device__ inline float wave_reduce_max(float v) {
    #pragma unroll
    for (int o = 32; o >= 1; o >>= 1) v = fmaxf(v, __shfl_xor(v, o, 64));
    return v;
}

__device__ inline ushort_t f2bf_rne(float f) {
    unsigned u = __float_as_uint(f);
    unsigned r = u + 0x7fffu + ((u >> 16) & 1u);
    return (ushort_t)(r >> 16);
}
__device__ inline float bf2f(ushort_t h) { return __uint_as_float(((unsigned)h) << 16); }

__device__ inline char q8(float f, float s) {
    int q = __float2int_rn(f * s);
    return (char)(q < -127 ? -127 : (q > 127 ? 127 : q));
}

__device__ inline void gload_lds16(const void* gsrc, void* ldst) {
    __builtin_amdgcn_global_load_lds(
        (const __attribute__((address_space(1))) unsigned int*)gsrc,
        (__attribute__((address_space(3))) unsigned int*)ldst, 16, 0, 0);
}

// sorted-pair compare-exchange helpers (explicit value+index)
__device__ inline void ce4(float& v0, int& j0, float& v1, int& j1) {
    bool sw = (v1 < v0) || (v1 == v0 && j1 < j0);
    float tv = sw ? v1 : v0, uv = sw ? v0 : v1;
    int tj = sw ? j1 : j0, uj = sw ? j0 : j1;
    v0 = tv; j0 = tj; v1 = uv; j1 = uj;
}
__device__ inline void pickmin(float& v, int& j, float bv, int bj) {
    if (bv < v || (bv == v && bj < j)) { v = bv; j = bj; }
}

// ================= fused prep: cbq | aq | wsplit | wgemm_split =================
__global__ __launch_bounds__(256) void prep_kernel(const float* __restrict__ CB,
                                                   const float* __restrict__ X,
                                                   const float* __restrict__ att_w,
                                                   const float* __restrict__ ex_w,
                                                   const float* __restrict__ qkv_w,
                                                   const float* __restrict__ proj_w,
                                                   char* __restrict__ CBq,
                                                   float* __restrict__ cnq,
                                                   char* __restrict__ Aq,
                                                   ushort_t* __restrict__ attHi,
                                                   char* __restrict__ exq,
                                                   ushort_t* __restrict__ wqkvF,
                                                   ushort_t* __restrict__ wprojF) {
    __shared__ float xs[16 * 776];
    __shared__ float red[4][16];
    const int bid = blockIdx.x;
    const int t = threadIdx.x;
    if (bid < 1296) {
        // ---- cbq (bid<512) or aq (512..1295): 16-row fp32 -> int8 frags ----
        const bool isCB = bid < 512;
        const int blk = isCB ? bid : bid - 512;
        const float* src0 = isCB ? CB : X;
        char* dst = isCB ? CBq : Aq;
        const float4* src = (const float4*)(src0 + (size_t)blk * 16 * C_);
        #pragma unroll
        for (int i = 0; i < 12; ++i) {
            int idx4 = t + i * 256;
            int r = idx4 / 192, c4 = idx4 - r * 192;
            ((float4*)(xs + r * 776))[c4] = src[idx4];
        }
        __syncthreads();
        #pragma unroll
        for (int i = 0; i < 3; ++i) {
            int s = t + i * 256;
            int kb = s >> 6, l = s & 63;
            int row = l & 15;
            int k0 = kb * 64 + ((l >> 4) << 4);
            union { char c[16]; i32x4 v; } Q;
            #pragma unroll
            for (int e = 0; e < 16; ++e) Q.c[e] = q8(xs[row * 776 + k0 + e], 32.f);
            *(i32x4*)&dst[(((size_t)blk * 12 + kb) << 10) + l * 16] = Q.v;
        }
        if (isCB) {
            int row = t & 15, chunk = t >> 4;
            float sum = 0.f;
            #pragma unroll
            for (int j = 0; j < 48; ++j) { float v = xs[row * 776 + chunk * 48 + j]; sum += v * v; }
            sum += __shfl_xor(sum, 16, 64);
            sum += __shfl_xor(sum, 32, 64);
            if ((t & 63) < 16) red[t >> 6][t & 15] = sum;
            __syncthreads();
            if (t < 16) cnq[blk * 16 + t] = (red[0][t] + red[1][t] + red[2][t] + red[3][t]) * 1024.f;
        }
    } else if (bid < 1329) {
        // ---- wsplit: att bf16 frags + ex int8 frags ----
        int gid = (bid - 1296) * 256 + t;
        if (gid < 7680) {
            int cb = gid / 1536;
            int rem = gid - cb * 1536;
            int l = rem & 63;
            int col = cb * 16 + (l & 15);
            int k = ((rem >> 6) << 5) + ((l >> 4) << 3);
            union { ushort_t u[8]; short8v v; } H;
            #pragma unroll
            for (int e = 0; e < 8; ++e) {
                int c = k + e;
                float f = (col < 72) ? att_w[(size_t)(col & 7) * 6912 + c * 9 + (col >> 3)] : 0.f;
                H.u[e] = f2bf_rne(f);
            }
            *(short8v*)&attHi[(size_t)gid * 8] = H.v;
        } else if (gid < 8448) {
            int g2 = gid - 7680;
            int l = g2 & 63;
            int col = l & 15;
            int k0 = ((g2 >> 6) << 6) + ((l >> 4) << 4);
            union { char c[16]; i32x4 v; } Q;
            #pragma unroll
            for (int e = 0; e < 16; ++e) {
                int k = k0 + e;
                float f = (col < 9) ? ex_w[k * 9 + col] : 0.f;
                Q.c[e] = q8(f, 1024.f);
            }
            *(i32x4*)&exq[(size_t)g2 * 16] = Q.v;
        }
    } else {
        // ---- wgemm_split: qkv/proj weights -> bf16 frags ----
        int gid = (bid - 1329) * 256 + t;
        const float* W; ushort_t* D; int g2;
        if (gid < 221184) { W = qkv_w; D = wqkvF; g2 = gid; }
        else { W = proj_w; D = wprojF; g2 = gid - 221184; }
        int cb = g2 / 1536;
        int rem = g2 - cb * 1536;
        int l = rem & 63;
        int col = cb * 16 + (l & 15);
        int k = ((rem >> 6) << 5) + ((l >> 4) << 3);
        union { ushort_t u[8]; short8v v; } H;
        #pragma unroll
        for (int e = 0; e < 8; ++e) H.u[e] = f2bf_rne(W[(size_t)col * 768 + k + e]);
        *(short8v*)&D[(size_t)g2 * 8] = H.v;
    }
}

// ========== VQ: int8 MFMA, BN=256, 2-barrier counted pipeline, g=16 ==========
// grid (16, 196). Tag in low 8 mantissa bits: (ch<<6)|(nf<<4)|r — perturbation
// <=256 scaled units << quant noise (~700): selection-only; fp64 rescore exact.
__global__ __launch_bounds__(256, 3) void vq_i8_kernel(const char* __restrict__ Aq,
                                                       const char* __restrict__ CBq,
                                                       const float* __restrict__ cnq,
                                                       float2* __restrict__ cand) {
    __shared__ __align__(16) char AqL[2][4096];
    __shared__ __align__(16) char BqL[2][16384];
    const int tid = threadIdx.x;
    const int l = tid & 63, w = tid >> 6;
    const int g = blockIdx.x;            // 0..15 code split (512 codes)
    const int mt = blockIdx.y;
    const int row0 = mt * 64;
    const int rg0 = mt * 4;

    // per-thread constant byte-offsets for this wave's 5 staged subtiles
    int K[5];
    #pragma unroll
    for (int i = 0; i < 5; ++i) {
        int s = w * 5 + i;
        K[i] = ((s < 4) ? (rg0 + s) * 12288 : (g * 32 + (s - 4)) * 12288) + l * 16;
    }
    float cnr[2][4];
    #pragma unroll
    for (int ch = 0; ch < 2; ++ch)
        #pragma unroll
        for (int nf = 0; nf < 4; ++nf)
            cnr[ch][nf] = cnq[g * 512 + ch * 256 + (w * 4 + nf) * 16 + (l & 15)];

    float v1[4][4], v2[4][4];
    #pragma unroll
    for (int mf = 0; mf < 4; ++mf)
        #pragma unroll
        for (int rg = 0; rg < 4; ++rg) { v1[mf][rg] = BIGF; v2[mf][rg] = BIGF; }

    auto STAGE = [&](int buf, int oA, int oB) {
        #pragma unroll
        for (int i = 0; i < 5; ++i) {
            int s = w * 5 + i;
            if (s < 4)
                gload_lds16((const char*)Aq + (unsigned)(K[i] + oA), &AqL[buf][s << 10]);
            else
                gload_lds16((const char*)CBq + (unsigned)(K[i] + oB), &BqL[buf][(s - 4) << 10]);
        }
    };

    int cur = 0;
    STAGE(0, 0, 0);                       // stage 0 -> buf0
    int sA = 1024, sB = 1024;             // offsets for stage u+1

    #pragma unroll 1
    for (int ch = 0; ch < 2; ++ch) {
        i32x4 acc[4][4];
        #pragma unroll
        for (int mf = 0; mf < 4; ++mf)
            #pragma unroll
            for (int nf = 0; nf < 4; ++nf) acc[mf][nf] = (i32x4){0, 0, 0, 0};

        #pragma unroll 1
        for (int st = 0; st < 12; ++st) {
            int u = ch * 12 + st;
            if (u < 23) {
                STAGE(cur ^ 1, sA, sB);                // issue stage u+1
                bool wrap = (((u + 1) % 12) == 11);
                sA += wrap ? -11264 : 1024;
                sB += wrap ? 185344 : 1024;            // +16*12288 - 11*1024
                asm volatile("s_waitcnt vmcnt(5)" ::: "memory");   // my u-loads landed
            } else {
                asm volatile("s_waitcnt vmcnt(0)" ::: "memory");
            }
            __builtin_amdgcn_sched_barrier(0);
            __builtin_amdgcn_s_barrier();              // B1: everyone's u-loads landed
            __builtin_amdgcn_sched_barrier(0);
            i32x4 aq[4];
            #pragma unroll
            for (int mf = 0; mf < 4; ++mf)
                aq[mf] = *(const i32x4*)&AqL[cur][(mf << 10) + l * 16];
            __builtin_amdgcn_s_setprio(1);
            #pragma unroll
            for (int nf = 0; nf < 4; ++nf) {
                i32x4 bq = *(const i32x4*)&BqL[cur][((w * 4 + nf) << 10) + l * 16];
                #pragma unroll
                for (int mf = 0; mf < 4; ++mf)
                    acc[mf][nf] = __builtin_amdgcn_mfma_i32_16x16x64_i8(aq[mf], bq, acc[mf][nf], 0, 0, 0);
            }
            __builtin_amdgcn_s_setprio(0);
            __builtin_amdgcn_sched_barrier(0);
            __builtin_amdgcn_s_barrier();              // B2: reads done before next overwrite
            __builtin_amdgcn_sched_barrier(0);
            cur ^= 1;
        }
        // chunk epilogue: packed-tag top-2 insert (3 float ops/value)
        #pragma unroll
        for (int nf = 0; nf < 4; ++nf) {
            float cnv = cnr[ch][nf];
            unsigned tag = ((unsigned)ch << 6) | ((unsigned)nf << 4) | (unsigned)(l & 15);
            #pragma unroll
            for (int mf = 0; mf < 4; ++mf)
                #pragma unroll
                for (int rg = 0; rg < 4; ++rg) {
                    float d = fmaf(-2.f, (float)acc[mf][nf][rg], cnv);
                    float dp = __uint_as_float((__float_as_uint(d) & 0xFFFFFF00u) | tag);
                    float t = fmaxf(v1[mf][rg], dp);
                    v1[mf][rg] = fminf(v1[mf][rg], dp);
                    v2[mf][rg] = fminf(v2[mf][rg], t);
                }
        }
    }
    // cross-lane top-2 merge over the 16 col-lanes; write (g,w) subset pair
    #pragma unroll
    for (int mf = 0; mf < 4; ++mf)
        #pragma unroll
        for (int rg = 0; rg < 4; ++rg) {
            float a1 = v1[mf][rg], a2 = v2[mf][rg];
            #pragma unroll
            for (int off = 8; off >= 1; off >>= 1) {
                float b1 = __shfl_xor(a1, off, 64), b2 = __shfl_xor(a2, off, 64);
                float m1 = fminf(a1, b1);
                float t  = fmaxf(a1, b1);
                a2 = fminf(t, fminf(a2, b2));
                a1 = m1;
            }
            if ((l & 15) == 0) {
                int row = row0 + mf * 16 + (l >> 4) * 4 + rg;
                cand[(size_t)row * 64 + g * 4 + w] = make_float2(a1, a2);
            }
        }
}

// ========== post1: convgemm_i8 (bid<98) | rescore (bid>=98) ==========
__global__ __launch_bounds__(256) void post1_kernel(const char* __restrict__ Aq,
                                                    const char* __restrict__ exq,
                                                    float* __restrict__ XW,
                                                    const float2* __restrict__ cand,
                                                    const float* __restrict__ X,
                                                    const float* __restrict__ CB,
                                                    int* __restrict__ idx,
                                                    float* __restrict__ encOut) {
    __shared__ __align__(16) char AqL[8 * 1024];
    __shared__ __align__(16) char BqL[1024];
    if (blockIdx.x < 98) {
        // ---- motion conv GEMM (int8): XW[12544][16] ----
        const int tid = threadIdx.x;
        const int l = tid & 63, w = tid >> 6;
        const int rg0 = blockIdx.x * 8, row0 = blockIdx.x * 128;
        i32x4 acc[2];
        acc[0] = (i32x4){0, 0, 0, 0}; acc[1] = (i32x4){0, 0, 0, 0};
        #pragma unroll 1
        for (int st = 0; st < 12; ++st) {
            __syncthreads();
            #pragma unroll
            for (int i = 0; i < 3; ++i) {
                int s = w * 3 + i;
                if (s < 8)
                    gload_lds16(&Aq[(((size_t)(rg0 + s) * 12 + st) << 10) + l * 16], &AqL[s << 10]);
                else if (s == 8)
                    gload_lds16(&exq[((size_t)st << 10) + l * 16], &BqL[0]);
            }
            __syncthreads();
            i32x4 bq = *(const i32x4*)&BqL[l * 16];
            #pragma unroll
            for (int mf = 0; mf < 2; ++mf) {
                i32x4 aq = *(const i32x4*)&AqL[((w * 2 + mf) << 10) + l * 16];
                acc[mf] = __builtin_amdgcn_mfma_i32_16x16x64_i8(aq, bq, acc[mf], 0, 0, 0);
            }
        }
        #pragma unroll
        for (int mf = 0; mf < 2; ++mf)
            #pragma unroll
            for (int rg = 0; rg < 4; ++rg) {
                int row = row0 + w * 32 + mf * 16 + (l >> 4) * 4 + rg;
                XW[(size_t)row * 16 + (l & 15)] = (float)acc[mf][rg] * (1.f / 32768.f);
            }
    } else {
        // ---- rescore: top-4 of 64 subset-pairs (explicit idx), fp64 re-eval ----
        int bid = blockIdx.x - 98;
        int w4 = threadIdx.x >> 6, l = threadIdx.x & 63;
        int r = bid * 4 + w4;
        float2 c = cand[(size_t)r * 64 + l];
        unsigned b0 = __float_as_uint(c.x), b1 = __float_as_uint(c.y);
        int gg = l >> 2, ww = l & 3;
        int j0 = gg * 512 + (int)((b0 >> 6) & 1) * 256 + (ww * 4 + (int)((b0 >> 4) & 3)) * 16 + (int)(b0 & 15);
        int j1 = gg * 512 + (int)((b1 >> 6) & 1) * 256 + (ww * 4 + (int)((b1 >> 4) & 3)) * 16 + (int)(b1 & 15);
        float a0 = c.x, a1 = c.y, a2 = BIGF, a3 = BIGF;
        int j2 = 0x7fffffff, j3 = 0x7fffffff;
        #pragma unroll
        for (int off = 32; off >= 1; off >>= 1) {
            float b0f = __shfl_xor(a0, off, 64), b1f = __shfl_xor(a1, off, 64);
            float b2f = __shfl_xor(a2, off, 64), b3f = __shfl_xor(a3, off, 64);
            int p0 = __shfl_xor(j0, off, 64), p1 = __shfl_xor(j1, off, 64);
            int p2 = __shfl_xor(j2, off, 64), p3 = __shfl_xor(j3, off, 64);
            pickmin(a0, j0, b3f, p3); pickmin(a1, j1, b2f, p2);
            pickmin(a2, j2, b1f, p1); pickmin(a3, j3, b0f, p0);
            ce4(a0, j0, a2, j2); ce4(a1, j1, a3, j3);
            ce4(a0, j0, a1, j1); ce4(a2, j2, a3, j3);
        }
        double dot0 = 0, dot1 = 0, dot2 = 0, dot3 = 0;
        double nn0 = 0, nn1 = 0, nn2 = 0, nn3 = 0;
        const float* xr = X + (size_t)r * C_;
        #pragma unroll
        for (int jj = 0; jj < 12; ++jj) {
            int cc = l * 12 + jj;
            double x = (double)xr[cc];
            double c0 = (double)CB[(size_t)j0 * C_ + cc]; dot0 += x * c0; nn0 += c0 * c0;
            double c1 = (double)CB[(size_t)j1 * C_ + cc]; dot1 += x * c1; nn1 += c1 * c1;
            double c2 = (double)CB[(size_t)j2 * C_ + cc]; dot2 += x * c2; nn2 += c2 * c2;
            double c3 = (double)CB[(size_t)j3 * C_ + cc]; dot3 += x * c3; nn3 += c3 * c3;
        }
        #pragma unroll
        for (int off = 32; off >= 1; off >>= 1) {
            dot0 += __shfl_xor(dot0, off, 64); dot1 += __shfl_xor(dot1, off, 64);
            dot2 += __shfl_xor(dot2, off, 64); dot3 += __shfl_xor(dot3, off, 64);
            nn0 += __shfl_xor(nn0, off, 64); nn1 += __shfl_xor(nn1, off, 64);
            nn2 += __shfl_xor(nn2, off, 64); nn3 += __shfl_xor(nn3, off, 64);
        }
        if (l == 0) {
            double d0 = nn0 - 2.0 * dot0, d1 = nn1 - 2.0 * dot1;
            double d2 = nn2 - 2.0 * dot2, d3 = nn3 - 2.0 * dot3;
            double best = d0; int bi = j0;
            if (d1 < best || (d1 == best && j1 < bi)) { best = d1; bi = j1; }
            if (d2 < best || (d2 == best && j2 < bi)) { best = d2; bi = j2; }
            if (d3 < best || (d3 == best && j3 < bi)) { best = d3; bi = j3; }
            idx[r] = bi;
            encOut[r] = (float)bi;
        }
    }
}

// ---------------- bf16 conv GEMM (region mask): out[12544][NF*16] -----------
template<int NF>
__global__ __launch_bounds__(256) void convgemm_kernel(const ushort_t* __restrict__ Ahi_g,
                                                       const ushort_t* __restrict__ Bhi_g,
                                                       float* __restrict__ out) {
    __shared__ __align__(16) ushort_t AhL[16 * 512];
    __shared__ __align__(16) ushort_t BhL[NF * 2 * 512];
    const int TOT = 16 + 2 * NF;
    const int PW = (TOT + 3) >> 2;
    const int tid = threadIdx.x;
    const int l = tid & 63, w = tid >> 6;
    const int rg0 = blockIdx.x * 8;
    const int row0 = blockIdx.x * 128;
    f32x4 acc[2][NF];
    #pragma unroll
    for (int mf = 0; mf < 2; ++mf)
        #pragma unroll
        for (int nf = 0; nf < NF; ++nf) acc[mf][nf] = (f32x4){0.f, 0.f, 0.f, 0.f};
    #pragma unroll 1
    for (int st = 0; st < 12; ++st) {
        __syncthreads();
        #pragma unroll
        for (int i = 0; i < PW; ++i) {
            int s = w * PW + i;
            if (s < 16) {
                int rb = s >> 1, kb = s & 1;
                gload_lds16(&Ahi_g[(((size_t)(rg0 + rb) * 24 + st * 2 + kb) << 9) + l * 8], &AhL[s << 9]);
            } else if (s < TOT) {
                int t2 = s - 16;
                int cb = t2 >> 1, kb = t2 & 1;
                gload_lds16(&Bhi_g[(((size_t)cb * 24 + st * 2 + kb) << 9) + l * 8], &BhL[t2 << 9]);
            }
        }
        __syncthreads();
        #pragma unroll
        for (int kf = 0; kf < 2; ++kf) {
            short8v ah[2];
            #pragma unroll
            for (int mf = 0; mf < 2; ++mf)
                ah[mf] = *(const short8v*)&AhL[(((w * 2 + mf) * 2 + kf) << 9) + l * 8];
            #pragma unroll
            for (int nf = 0; nf < NF; ++nf) {
                short8v bh = *(const short8v*)&BhL[((nf * 2 + kf) << 9) + l * 8];
                #pragma unroll
                for (int mf = 0; mf < 2; ++mf)
                    acc[mf][nf] = __builtin_amdgcn_mfma_f32_16x16x32_bf16(ah[mf], bh, acc[mf][nf], 0, 0, 0);
            }
        }
    }
    #pragma unroll
    for (int mf = 0; mf < 2; ++mf)
        #pragma unroll
        for (int nf = 0; nf < NF; ++nf)
            #pragma unroll
            for (int rg = 0; rg < 4; ++rg) {
                int row = row0 + w * 32 + mf * 16 + (l >> 4) * 4 + rg;
                out[(size_t)row * (NF * 16) + nf * 16 + (l & 15)] = acc[mf][nf][rg];
            }
}

// ---------------- generic frag-GEMM with bias: out[M][N] fp32 ----------------
template<int NF>
__global__ __launch_bounds__(256) void gemm_frag_kernel(const ushort_t* __restrict__ Af,
                                                        const ushort_t* __restrict__ Bf,
                                                        const float* __restrict__ bias,
                                                        float* __restrict__ out, int N) {
    __shared__ __align__(16) ushort_t AhL[16 * 512];
    __shared__ __align__(16) ushort_t BhL[2 * NF * 512];
    const int TOT = 16 + 2 * NF;
    const int PW = (TOT + 3) >> 2;
    const int tid = threadIdx.x;
    const int l = tid & 63, w = tid >> 6;
    const int rg0 = blockIdx.x * 8, row0 = blockIdx.x * 128;
    const int cb0 = blockIdx.y * NF;
    f32x4 acc[2][NF];
    #pragma unroll
    for (int mf = 0; mf < 2; ++mf)
        #pragma unroll
        for (int nf = 0; nf < NF; ++nf) acc[mf][nf] = (f32x4){0.f, 0.f, 0.f, 0.f};
    #pragma unroll 1
    for (int st = 0; st < 12; ++st) {
        __syncthreads();
        #pragma unroll
        for (int i = 0; i < PW; ++i) {
            int s = w * PW + i;
            if (s < 16) {
                int rb = s >> 1, kb = s & 1;
                gload_lds16(&Af[(((size_t)(rg0 + rb) * 24 + st * 2 + kb) << 9) + l * 8], &AhL[s << 9]);
            } else if (s < TOT) {
                int t2 = s - 16;
                int cb = t2 >> 1, kb = t2 & 1;
                gload_lds16(&Bf[(((size_t)(cb0 + cb) * 24 + st * 2 + kb) << 9) + l * 8], &BhL[t2 << 9]);
            }
        }
        __syncthreads();
        #pragma unroll
        for (int kf = 0; kf < 2; ++kf) {
            short8v ah[2];
            #pragma unroll
            for (int mf = 0; mf < 2; ++mf)
                ah[mf] = *(const short8v*)&AhL[(((w * 2 + mf) * 2 + kf) << 9) + l * 8];
            #pragma unroll
            for (int nf = 0; nf < NF; ++nf) {
                short8v bh = *(const short8v*)&BhL[((nf * 2 + kf) << 9) + l * 8];
                #pragma unroll
                for (int mf = 0; mf < 2; ++mf)
                    acc[mf][nf] = __builtin_amdgcn_mfma_f32_16x16x32_bf16(ah[mf], bh, acc[mf][nf], 0, 0, 0);
            }
        }
    }
    #pragma unroll
    for (int mf = 0; mf < 2; ++mf)
        #pragma unroll
        for (int nf = 0; nf < NF; ++nf) {
            int col = (cb0 + nf) * 16 + (l & 15);
            float bv = bias[col];
            #pragma unroll
            for (int rg = 0; rg < 4; ++rg) {
                int row = row0 + w * 32 + mf * 16 + (l >> 4) * 4 + rg;
                out[(size_t)row * N + col] = acc[mf][nf][rg] + bv;
            }
        }
}

// ---------------- mm finish: shifted-add + frame diff + softmax --------------
__global__ __launch_bounds__(256) void mm_finish_kernel(const float* __restrict__ XW,
                                                        const float* __restrict__ ex_b,
                                                        float* __restrict__ sm) {
    int b = blockIdx.x, t = threadIdx.x;
    float val = -INFINITY;
    if (t < L_) {
        if ((b & 3) == 0) val = ex_b[0];
        else {
            int yy = t / HW_, xx = t - (t / HW_) * HW_;
            float acc = 0.f;
            #pragma unroll
            for (int dy = 0; dy < 3; ++dy) {
                int sy = yy + dy - 1; if (sy < 0 || sy >= HW_) continue;
                #pragma unroll
                for (int dx = 0; dx < 3; ++dx) {
                    int sx = xx + dx - 1; if (sx < 0 || sx >= HW_) continue;
                    int q = sy * HW_ + sx, tap = dy * 3 + dx;
                    acc += XW[((size_t)b * L_ + q) * 16 + tap]
                         - XW[((size_t)(b - 1) * L_ + q) * 16 + tap];
                }
            }
            val = acc + ex_b[0];
        }
    }
    __shared__ float red[4];
    float mw = wave_reduce_max(val);
    if ((t & 63) == 0) red[t >> 6] = mw;
    __syncthreads();
    float mx = fmaxf(fmaxf(red[0], red[1]), fmaxf(red[2], red[3]));
    float e = (t < L_) ? expf(val - mx) : 0.f;
    __syncthreads();
    float sw = wave_reduce_sum(e);
    if ((t & 63) == 0) red[t >> 6] = sw;
    __syncthreads();
    float s = red[0] + red[1] + red[2] + red[3];
    if (t < L_) sm[b * L_ + t] = e / s;
}

// ---------------- vqf -> fragment-linear bf16 ----------------
__global__ __launch_bounds__(256) void vqf_split_kernel(const float* __restrict__ X,
                                                        const float* __restrict__ CB,
                                                        const int* __restrict__ idx,
                                                        const float* __restrict__ sm,
                                                        ushort_t* __restrict__ Vhi) {
    const int rg = blockIdx.x, t = threadIdx.x;
    #pragma unroll
    for (int i = 0; i < 6; ++i) {
        int s = t + i * 256;
        int kb = s >> 6, l = s & 63;
        int row = rg * 16 + (l & 15);
        int k = kb * 32 + ((l >> 4) << 3);
        int kidx = idx[row];
        float sc = sm[row];
        const float* xp = &X[(size_t)row * C_ + k];
        const float* cp = &CB[(size_t)kidx * C_ + k];
        union { ushort_t u[8]; short8v v; } H;
        #pragma unroll
        for (int e = 0; e < 8; ++e) H.u[e] = f2bf_rne(cp[e] + xp[e] * sc);
        *(short8v*)&Vhi[((size_t)rg * 1536 + s) * 8] = H.v;
    }
}

// ------- regions (fused rm_finish): rms from OUTC in-block, einsum, outputs ---
__global__ __launch_bounds__(256) void regions_kernel(const ushort_t* __restrict__ Vhi,
                                                      const float* __restrict__ OUTC,
                                                      const float* __restrict__ att_b,
                                                      float* __restrict__ rmOut,
                                                      ushort_t* __restrict__ seqF) {
    int b = blockIdx.x, cg = blockIdx.y, t = threadIdx.x;
    __shared__ float rms[R_ * L_];
    for (int i = t; i < R_ * L_; i += 256) {
        int r = i / L_, p = i - r * L_;
        int yy = p / HW_, xx = p - yy * HW_;
        float acc = att_b[r];
        #pragma unroll
        for (int dy = 0; dy < 3; ++dy) {
            int sy = yy + dy - 1; if (sy < 0 || sy >= HW_) continue;
            #pragma unroll
            for (int dx = 0; dx < 3; ++dx) {
                int sx = xx + dx - 1; if (sx < 0 || sx >= HW_) continue;
                int q = sy * HW_ + sx, tap = dy * 3 + dx;
                acc += OUTC[((size_t)b * L_ + q) * 80 + tap * 8 + r];
            }
        }
        rms[i] = acc;
        if (cg == 0) rmOut[((size_t)b * R_ + r) * L_ + p] = acc;
    }
    __syncthreads();
    const float inv = 1.f / 196.f;
    int c = cg * 256 + t;
    int kb = c >> 5, q = (c >> 3) & 3, e = c & 7;
    float acc[R_] = {};
    for (int p = 0; p < L_; ++p) {
        int row = b * L_ + p;
        int rg = row >> 4, rr = row & 15;
        size_t a = (((size_t)rg * 24 + kb) * 64 + q * 16 + rr) * 8 + e;
        float x = bf2f(Vhi[a]);
        #pragma unroll
        for (int r = 0; r < R_; ++r) acc[r] += x * rms[r * L_ + p];
    }
    #pragma unroll
    for (int r = 0; r < R_; ++r) {
        int row = b * 8 + r;
        int rg2 = row >> 4, rr = row & 15;
        seqF[(((size_t)rg2 * 24 + kb) * 64 + q * 16 + rr) * 8 + e] = f2bf_rne(acc[r] * inv);
    }
}

// ---------------- per-(batch,head) attention -> frag-linear bf16 out ---------
__global__ __launch_bounds__(256) void attn_kernel(const float* __restrict__ qkv,
                                                   ushort_t* __restrict__ outF) {
    int bp = blockIdx.x, h = blockIdx.y;
    __shared__ float qs[NT_][DH_], ks[NT_][DH_], vs[NT_][DH_];
    __shared__ float sc[NT_][NT_ + 1];
    int tid = threadIdx.x;
    for (int e = tid; e < NT_ * DH_; e += 256) {
        int n = e / DH_, d = e - n * DH_;
        size_t base = ((size_t)(bp * NT_ + n)) * 2304 + h * DH_ + d;
        qs[n][d] = qkv[base];
        ks[n][d] = qkv[base + 768];
        vs[n][d] = qkv[base + 1536];
    }
    __syncthreads();
    const float scale = 1.0f / sqrtf((float)DH_);
    for (int e = tid; e < NT_ * NT_; e += 256) {
        int n = e >> 5, m = e & 31;
        float s = 0.f;
        #pragma unroll 8
        for (int d = 0; d < DH_; ++d) s += qs[n][d] * ks[m][d];
        sc[n][m] = s * scale;
    }
    __syncthreads();
    if (tid < NT_) {
        float mx = -INFINITY;
        #pragma unroll
        for (int m = 0; m < NT_; ++m) mx = fmaxf(mx, sc[tid][m]);
        float sum = 0.f;
        #pragma unroll
        for (int m = 0; m < NT_; ++m) { float e2 = expf(sc[tid][m] - mx); sc[tid][m] = e2; sum += e2; }
        float inv = 1.f / sum;
        #pragma unroll
        for (int m = 0; m < NT_; ++m) sc[tid][m] *= inv;
    }
    __syncthreads();
    for (int e = tid; e < NT_ * DH_; e += 256) {
        int n = e / DH_, d = e - n * DH_;
        float o = 0.f;
        #pragma unroll
        for (int m = 0; m < NT_; ++m) o += sc[n][m] * vs[m][d];
        int row = bp * NT_ + n, c = h * DH_ + d;
        outF[(((size_t)(row >> 4) * 24 + (c >> 5)) * 64 + ((c >> 3) & 3) * 16 + (row & 15)) * 8 + (c & 7)]
            = f2bf_rne(o);
    }
}

// ---------------- launch ----------------
extern "C" void kernel_launch(void* const* d_in, const int* in_sizes, int n_in,
                              void* d_out, int out_size, void* d_ws, size_t ws_size,
                              hipStream_t stream) {
    const float* in_feas  = (const float*)d_in[0];
    const float* codebook = (const float*)d_in[2];
    const float* att_w    = (const float*)d_in[3];
    const float* att_b    = (const float*)d_in[4];
    const float* ex_w     = (const float*)d_in[5];
    const float* ex_b     = (const float*)d_in[6];
    const float* qkv_w    = (const float*)d_in[7];
    const float* qkv_b    = (const float*)d_in[8];
    const float* proj_w   = (const float*)d_in[9];
    const float* proj_b   = (const float*)d_in[10];

    float* out    = (float*)d_out;
    float* outVd  = out;
    float* outEnc = out + 393216;
    float* outRm  = out + 393216 + 12544;

    float* ws = (float*)d_ws;
    float*    cnq    = ws + 0;                          // 8,192
    float2*   cand   = (float2*)(ws + 8192);            // 12544*64*2 fl = 1,605,632
    char*     CBq    = (char*)(ws + 1613824);           // 1,572,864 fl
    char*     Aq     = (char*)(ws + 3186688);           // 2,408,448 fl
    ushort_t* attHi  = (ushort_t*)(ws + 5595136);       // 30,720 fl
    char*     exq    = (char*)(ws + 5625856);           // 3,072 fl
    ushort_t* wqkvF  = (ushort_t*)(ws + 5628928);       // 884,736 fl
    ushort_t* wprojF = (ushort_t*)(ws + 6513664);       // 294,912 fl
    int*      idx    = (int*)(ws + 6808576);            // 12,544
    float*    XW     = ws + 6821120;                    // 200,704
    float*    sm     = ws + 7021824;                    // 12,544
    ushort_t* Vhi    = (ushort_t*)(ws + 7034368);       // 4,816,896 fl
    float*    OUTC   = ws + 11851264;                   // 1,003,520
    ushort_t* seqF   = (ushort_t*)(ws + 12854784);      // 196,608 fl
    float*    qkvb   = ws + 13051392;                   // 1,179,648
    ushort_t* attnbF = (ushort_t*)(ws + 14231040);      // 196,608 fl -> 14,427,648

    hipLaunchKernelGGL(prep_kernel, dim3(2481), dim3(256), 0, stream,
                       codebook, in_feas, att_w, ex_w, qkv_w, proj_w,
                       CBq, cnq, Aq, attHi, exq, wqkvF, wprojF);
    hipLaunchKernelGGL(vq_i8_kernel, dim3(16, 196), dim3(256), 0, stream, Aq, CBq, cnq, cand);
    hipLaunchKernelGGL(post1_kernel, dim3(98 + 3136), dim3(256), 0, stream,
                       Aq, exq, XW, cand, in_feas, codebook, idx, outEnc);
    hipLaunchKernelGGL(mm_finish_kernel, dim3(B_), dim3(256), 0, stream, XW, ex_b, sm);
    hipLaunchKernelGGL(vqf_split_kernel, dim3(784), dim3(256), 0, stream,
                       in_feas, codebook, idx, sm, Vhi);
    hipLaunchKernelGGL((convgemm_kernel<5>), dim3(98), dim3(256), 0, stream, Vhi, attHi, OUTC);
    hipLaunchKernelGGL(regions_kernel, dim3(B_, 3), dim3(256), 0, stream,
                       Vhi, OUTC, att_b, outRm, seqF);
    hipLaunchKernelGGL((gemm_frag_kernel<8>), dim3(4, 18), dim3(256), 0, stream,
                       seqF, wqkvF, qkv_b, qkvb, 2304);
    hipLaunchKernelGGL(attn_kernel, dim3(BP_, NH_), dim3(256), 0, stream, qkvb, attnbF);
    hipLaunchKernelGGL((gemm_frag_kernel<8>), dim3(4, 6), dim3(256), 0, stream,
                       attnbF, wprojF, proj_b, outVd, 768);
}